// Round 4
// baseline (2659.445 us; speedup 1.0000x reference)
//
#include <hip/hip_runtime.h>
#include <hip/hip_bf16.h>
#include <math.h>

typedef __hip_bfloat16 bf16;
typedef __bf16 bf16x8 __attribute__((ext_vector_type(8)));
typedef float f32x4 __attribute__((ext_vector_type(4)));

__device__ __forceinline__ float b2f(bf16 v){ return __bfloat162float(v); }
__device__ __forceinline__ bf16  f2b(float v){ return __float2bfloat16(v); }

// async global->LDS, 16B per lane; LDS dest = wave-uniform base + lane*16
__device__ __forceinline__ void gl_lds16(const bf16* g, bf16* l) {
    __builtin_amdgcn_global_load_lds((const __attribute__((address_space(1))) unsigned int*)g,
                                     (__attribute__((address_space(3))) unsigned int*)l, 16, 0, 0);
}

// ---------------- deck means ----------------
__global__ __launch_bounds__(256) void deckmean_k(const int* __restrict__ deck, const int* __restrict__ opp,
                                                  const float* __restrict__ tok, float* __restrict__ deckm)
{
    int b = blockIdx.x, w = blockIdx.y;
    const int* dk = (w ? opp : deck) + b * 8;
    int idx[8];
    #pragma unroll
    for (int j = 0; j < 8; j++) idx[j] = dk[j];
    float* out = deckm + (size_t)(w * 16 + b) * 768;
    for (int d = threadIdx.x; d < 768; d += 256) {
        float s = 0.f;
        #pragma unroll
        for (int j = 0; j < 8; j++) s += tok[(size_t)idx[j] * 768 + d];
        out[d] = s * 0.125f;
    }
}

// ---------------- mask + last_idx ----------------
__global__ __launch_bounds__(512) void mask_k(const int* __restrict__ cards, int* __restrict__ maskb,
                                              int* __restrict__ lastidx)
{
    int b = blockIdx.x, t = threadIdx.x;
    int m = (cards[b * 512 + t] != 0) ? 1 : 0;
    maskb[b * 512 + t] = m;
    __shared__ int red[512];
    red[t] = m; __syncthreads();
    for (int st = 256; st > 0; st >>= 1) { if (t < st) red[t] += red[t + st]; __syncthreads(); }
    if (t == 0) {
        int cnt = red[0];
        if (cnt == 0) { maskb[b * 512] = 1; cnt = 1; }  // all-pad fix
        lastidx[b] = cnt - 1;
    }
}

// ---------------- embedding sum -> fp32 residual stream ----------------
__global__ __launch_bounds__(256) void embed_k(const int* __restrict__ cards, const int* __restrict__ players,
                                               const float* __restrict__ tok, const float* __restrict__ pemb,
                                               const float* __restrict__ pos, const float* __restrict__ deckm,
                                               float* __restrict__ x)
{
    int t = blockIdx.x;
    int b = t >> 9, ti = t & 511;
    int cd = cards[t];
    int p = players[t]; p = p < 0 ? 0 : (p > 1 ? 1 : p);
    const float* tr  = tok  + (size_t)cd * 768;
    const float* pr  = pemb + (size_t)p  * 768;
    const float* po  = pos  + (size_t)ti * 768;
    const float* dm = deckm + (size_t)b * 768;
    const float* om = deckm + (size_t)(16 + b) * 768;
    float* xr = x + (size_t)t * 768;
    for (int d = threadIdx.x; d < 768; d += 256)
        xr[d] = tr[d] + pr[d] + po[d] + dm[d] + om[d];
}

// ---------------- layernorm: fp32 in -> bf16 out ----------------
__global__ __launch_bounds__(256) void ln_k(const float* __restrict__ x, const float* __restrict__ s,
                                            const float* __restrict__ b, bf16* __restrict__ out)
{
    int row = blockIdx.x, tid = threadIdx.x;
    const float* xr = x + (size_t)row * 768;
    float v0 = xr[tid], v1 = xr[tid + 256], v2 = xr[tid + 512];
    __shared__ float rs[256], rq[256];
    rs[tid] = v0 + v1 + v2; rq[tid] = v0 * v0 + v1 * v1 + v2 * v2;
    __syncthreads();
    for (int st = 128; st > 0; st >>= 1) {
        if (tid < st) { rs[tid] += rs[tid + st]; rq[tid] += rq[tid + st]; }
        __syncthreads();
    }
    float mean = rs[0] * (1.f / 768.f);
    float var  = rq[0] * (1.f / 768.f) - mean * mean;
    float rstd = rsqrtf(var + 1e-5f);
    bf16* orow = out + (size_t)row * 768;
    orow[tid]       = f2b((v0 - mean) * rstd * s[tid]       + b[tid]);
    orow[tid + 256] = f2b((v1 - mean) * rstd * s[tid + 256] + b[tid + 256]);
    orow[tid + 512] = f2b((v2 - mean) * rstd * s[tid + 512] + b[tid + 512]);
}

// ---------------- batched 32x32 transpose+downcast of one layer's 4 weight mats ----------------
// segments (tile counts): qkv 72x24=1728, proj 24x24=576, fc1 96x24=2304, fc2 24x96=2304 -> 6912
__global__ void transpose4_k(const float* __restrict__ qw, const float* __restrict__ pw,
                             const float* __restrict__ f1, const float* __restrict__ f2,
                             bf16* __restrict__ oq, bf16* __restrict__ op,
                             bf16* __restrict__ o1, bf16* __restrict__ o2)
{
    int t = blockIdx.x;
    const float* in; bf16* out; int K, N, nbx;
    if (t < 1728)      { in = qw; out = oq; K = 768;  N = 2304; nbx = 72; }
    else if (t < 2304) { in = pw; out = op; K = 768;  N = 768;  t -= 1728; nbx = 24; }
    else if (t < 4608) { in = f1; out = o1; K = 768;  N = 3072; t -= 2304; nbx = 96; }
    else               { in = f2; out = o2; K = 3072; N = 768;  t -= 4608; nbx = 24; }
    int n0 = (t % nbx) * 32, k0 = (t / nbx) * 32;
    __shared__ bf16 tl[32][33];
    int tx = threadIdx.x, ty = threadIdx.y;
    #pragma unroll
    for (int i = 0; i < 32; i += 8)
        tl[ty + i][tx] = f2b(in[(size_t)(k0 + ty + i) * N + n0 + tx]);
    __syncthreads();
    #pragma unroll
    for (int i = 0; i < 32; i += 8)
        out[(size_t)(n0 + ty + i) * K + k0 + tx] = tl[tx][ty + i];
}

// ---------------- MFMA GEMM (m97 staging + XCD swizzle + optional split-K atomic epilogue) ----------
// C[M=8192][N] = A @ BT^T (+bias, opt gelu). grid = (64*nb, 1, splitK).
// swizzle: xcd = bid&7 owns m-stripes [xcd*8, xcd*8+8), n fastest -> A-stripe re-reads stay in one L2.
// atomicOut: fp32 atomicAdd into outF (residual pre-resident); bias added by kc==0 only.
__global__ __launch_bounds__(256) void gemm_k(const bf16* __restrict__ A, const bf16* __restrict__ BT,
                                              const float* __restrict__ bias, const float* __restrict__ resid,
                                              float* __restrict__ outF, bf16* __restrict__ outB,
                                              int N, int K, int act, int nb, int splitK, int atomicOut)
{
    __shared__ __align__(16) bf16 Al[128 * 64];
    __shared__ __align__(16) bf16 Bl[128 * 64];
    const int tid = threadIdx.x;
    const int lane = tid & 63, wave = tid >> 6;
    const int quad = lane >> 4, l16 = lane & 15;
    const int wm = wave >> 1, wn = wave & 1;

    const int bid = blockIdx.x;
    const int xcd = bid & 7, slot = bid >> 3;
    const int m_loc = slot / nb, nbl = slot - m_loc * nb;
    const int m0 = (xcd * 8 + m_loc) * 128, n0 = nbl * 128;
    const int kc = blockIdx.z;
    const int Kp = K / splitK;
    const int kbeg = kc * Kp, kend = kbeg + Kp;

    f32x4 acc[4][4] = {};
    const int srow = wave * 32;
    const int grow = srow + (lane >> 3);
    const int gcol = (lane & 7) * 8;

    for (int k0 = kbeg; k0 < kend; k0 += 64) {
        #pragma unroll
        for (int i = 0; i < 4; i++) {
            gl_lds16(&A [(size_t)(m0 + grow + i * 8) * K + k0 + gcol], &Al[(srow + i * 8) * 64]);
            gl_lds16(&BT[(size_t)(n0 + grow + i * 8) * K + k0 + gcol], &Bl[(srow + i * 8) * 64]);
        }
        __syncthreads();
        #pragma unroll
        for (int kk = 0; kk < 64; kk += 32) {
            bf16x8 af[4], bfr[4];
            #pragma unroll
            for (int t = 0; t < 4; t++) {
                af[t]  = __builtin_bit_cast(bf16x8, *(const uint4*)(&Al[(wm * 64 + t * 16 + l16) * 64 + kk + quad * 8]));
                bfr[t] = __builtin_bit_cast(bf16x8, *(const uint4*)(&Bl[(wn * 64 + t * 16 + l16) * 64 + kk + quad * 8]));
            }
            #pragma unroll
            for (int tm = 0; tm < 4; tm++)
                #pragma unroll
                for (int tn = 0; tn < 4; tn++)
                    acc[tm][tn] = __builtin_amdgcn_mfma_f32_16x16x32_bf16(af[tm], bfr[tn], acc[tm][tn], 0, 0, 0);
        }
        __syncthreads();
    }

    float bv[4];
    #pragma unroll
    for (int tn = 0; tn < 4; tn++)
        bv[tn] = (kc == 0) ? bias[n0 + wn * 64 + tn * 16 + l16] : 0.f;

    #pragma unroll
    for (int tm = 0; tm < 4; tm++) {
        #pragma unroll
        for (int tn = 0; tn < 4; tn++) {
            int n = n0 + wn * 64 + tn * 16 + l16;
            #pragma unroll
            for (int r = 0; r < 4; r++) {
                int m = m0 + wm * 64 + tm * 16 + quad * 4 + r;   // C/D: col=lane&15, row=quad*4+reg
                float v = acc[tm][tn][r] + bv[tn];
                size_t off = (size_t)m * N + n;
                if (atomicOut) {
                    atomicAdd(&outF[off], v);
                } else {
                    if (act) v = 0.5f * v * (1.0f + erff(v * 0.70710678118654752f));
                    if (resid) v += resid[off];
                    if (outB) outB[off] = f2b(v);
                    else      outF[off] = v;
                }
            }
        }
    }
}

// ---------------- MFMA flash attention ----------------
__global__ __launch_bounds__(256) void attn_k(const bf16* __restrict__ qkv, const int* __restrict__ mask,
                                              bf16* __restrict__ y)
{
    const int qt = blockIdx.x, h = blockIdx.y, b = blockIdx.z;
    const int qbase = qt * 64, tokb = b * 512;
    __shared__ __align__(16) unsigned short Kl[128][72];
    __shared__ __align__(16) unsigned short Vt[64][136];
    __shared__ __align__(16) unsigned short Ql[64][72];
    __shared__ __align__(16) unsigned short Ptq[4][16][136];
    __shared__ float mkf[128];

    const int tid = threadIdx.x, wave = tid >> 6, lane = tid & 63;
    const int quad = lane >> 4, l16 = lane & 15;
    const int qi = qbase + wave * 16 + l16;

    {
        int row = tid >> 2, c0 = (tid & 3) * 16;
        const bf16* g = &qkv[(size_t)(tokb + qbase + row) * 2304 + h * 64 + c0];
        *(uint4*)&Ql[row][c0]     = *(const uint4*)(g);
        *(uint4*)&Ql[row][c0 + 8] = *(const uint4*)(g + 8);
    }
    __syncthreads();
    bf16x8 bq[2];
    bq[0] = __builtin_bit_cast(bf16x8, *(const uint4*)&Ql[wave * 16 + l16][quad * 8]);
    bq[1] = __builtin_bit_cast(bf16x8, *(const uint4*)&Ql[wave * 16 + l16][32 + quad * 8]);

    float m_i = -INFINITY, l_i = 0.f;
    f32x4 Oacc[4] = {};

    const int nst = (qbase >> 7) + 1;
    for (int s = 0; s < nst; s++) {
        const int j0 = s * 128;
        __syncthreads();
        {
            int key = tid >> 1, c0 = (tid & 1) * 32;
            const bf16* kg = &qkv[(size_t)(tokb + j0 + key) * 2304 + 768  + h * 64 + c0];
            const bf16* vg = &qkv[(size_t)(tokb + j0 + key) * 2304 + 1536 + h * 64 + c0];
            #pragma unroll
            for (int q = 0; q < 4; q++)
                *(uint4*)&Kl[key][c0 + q * 8] = *(const uint4*)(kg + q * 8);
            union { uint4 u[4]; unsigned short e[32]; } vv;
            #pragma unroll
            for (int q = 0; q < 4; q++) vv.u[q] = *(const uint4*)(vg + q * 8);
            #pragma unroll
            for (int j = 0; j < 32; j++) Vt[c0 + j][key] = vv.e[j];
            if (tid < 128) mkf[tid] = mask[b * 512 + j0 + tid] ? 0.f : -INFINITY;
        }
        __syncthreads();

        f32x4 sc[8] = {};
        #pragma unroll
        for (int kcc = 0; kcc < 8; kcc++) {
            bf16x8 af0 = __builtin_bit_cast(bf16x8, *(const uint4*)&Kl[kcc * 16 + l16][quad * 8]);
            bf16x8 af1 = __builtin_bit_cast(bf16x8, *(const uint4*)&Kl[kcc * 16 + l16][32 + quad * 8]);
            sc[kcc] = __builtin_amdgcn_mfma_f32_16x16x32_bf16(af0, bq[0], sc[kcc], 0, 0, 0);
            sc[kcc] = __builtin_amdgcn_mfma_f32_16x16x32_bf16(af1, bq[1], sc[kcc], 0, 0, 0);
        }

        float pv[8][4];
        float mx = -INFINITY;
        #pragma unroll
        for (int kcc = 0; kcc < 8; kcc++) {
            float4 mk4 = *(const float4*)&mkf[kcc * 16 + quad * 4];
            float mkr[4] = { mk4.x, mk4.y, mk4.z, mk4.w };
            #pragma unroll
            for (int r = 0; r < 4; r++) {
                int krel = kcc * 16 + quad * 4 + r;
                float sval = (j0 + krel <= qi) ? (sc[kcc][r] * 0.125f + mkr[r]) : -INFINITY;
                pv[kcc][r] = sval;
                mx = fmaxf(mx, sval);
            }
        }
        mx = fmaxf(mx, __shfl_xor(mx, 16, 64));
        mx = fmaxf(mx, __shfl_xor(mx, 32, 64));
        float mn = fmaxf(m_i, mx);
        float alpha = (mn == -INFINITY) ? 1.f : __expf(m_i - mn);
        float lsum = 0.f;
        #pragma unroll
        for (int kcc = 0; kcc < 8; kcc++)
            #pragma unroll
            for (int r = 0; r < 4; r++) {
                float pp = (pv[kcc][r] == -INFINITY) ? 0.f : __expf(pv[kcc][r] - mn);
                pv[kcc][r] = pp; lsum += pp;
            }
        lsum += __shfl_xor(lsum, 16, 64);
        lsum += __shfl_xor(lsum, 32, 64);
        m_i = mn; l_i = alpha * l_i + lsum;

        #pragma unroll
        for (int kcc = 0; kcc < 8; kcc++) {
            union { unsigned short e[4]; uint2 u; } pk;
            #pragma unroll
            for (int r = 0; r < 4; r++) pk.e[r] = __builtin_bit_cast(unsigned short, f2b(pv[kcc][r]));
            *(uint2*)&Ptq[wave][l16][kcc * 16 + quad * 4] = pk.u;
        }
        #pragma unroll
        for (int mc = 0; mc < 4; mc++)
            #pragma unroll
            for (int r = 0; r < 4; r++) Oacc[mc][r] *= alpha;

        __syncthreads();

        #pragma unroll
        for (int kcc = 0; kcc < 4; kcc++) {
            bf16x8 pb = __builtin_bit_cast(bf16x8, *(const uint4*)&Ptq[wave][l16][kcc * 32 + quad * 8]);
            #pragma unroll
            for (int mc = 0; mc < 4; mc++) {
                bf16x8 vf = __builtin_bit_cast(bf16x8, *(const uint4*)&Vt[mc * 16 + l16][kcc * 32 + quad * 8]);
                Oacc[mc] = __builtin_amdgcn_mfma_f32_16x16x32_bf16(vf, pb, Oacc[mc], 0, 0, 0);
            }
        }
    }

    float inv = (l_i > 0.f) ? 1.f / l_i : 0.f;
    const int tok = tokb + qbase + wave * 16 + l16;
    #pragma unroll
    for (int mc = 0; mc < 4; mc++)
        #pragma unroll
        for (int r = 0; r < 4; r++)
            y[(size_t)tok * 768 + h * 64 + mc * 16 + quad * 4 + r] = f2b(Oacc[mc][r] * inv);
}

// ---------------- final LN + last-token select + head (fp32) ----------------
__global__ __launch_bounds__(256) void head_k(const float* __restrict__ x, const int* __restrict__ lastidx,
                                              const float* __restrict__ ls, const float* __restrict__ lb,
                                              const float* __restrict__ hw, const float* __restrict__ hb,
                                              float* __restrict__ out)
{
    int b = blockIdx.x, tid = threadIdx.x;
    const float* xr = x + ((size_t)(b * 512 + lastidx[b])) * 768;
    float v0 = xr[tid], v1 = xr[tid + 256], v2 = xr[tid + 512];
    __shared__ float rs[256], rq[256];
    rs[tid] = v0 + v1 + v2; rq[tid] = v0 * v0 + v1 * v1 + v2 * v2;
    __syncthreads();
    for (int st = 128; st > 0; st >>= 1) {
        if (tid < st) { rs[tid] += rs[tid + st]; rq[tid] += rq[tid + st]; }
        __syncthreads();
    }
    float mean = rs[0] * (1.f / 768.f);
    float var  = rq[0] * (1.f / 768.f) - mean * mean;
    float rstd = rsqrtf(var + 1e-5f);
    float part[9];
    #pragma unroll
    for (int a = 0; a < 9; a++) part[a] = 0.f;
    float vv[3] = { v0, v1, v2 };
    #pragma unroll
    for (int e = 0; e < 3; e++) {
        int d = tid + e * 256;
        float xnv = (vv[e] - mean) * rstd * ls[d] + lb[d];
        #pragma unroll
        for (int a = 0; a < 9; a++) part[a] += xnv * hw[d * 9 + a];
    }
    __shared__ float r9[9][256];
    #pragma unroll
    for (int a = 0; a < 9; a++) r9[a][tid] = part[a];
    __syncthreads();
    for (int st = 128; st > 0; st >>= 1) {
        if (tid < st) {
            for (int a = 0; a < 9; a++) r9[a][tid] += r9[a][tid + st];
        }
        __syncthreads();
    }
    if (tid < 9) out[b * 9 + tid] = r9[tid][0] + hb[tid];
}

extern "C" void kernel_launch(void* const* d_in, const int* in_sizes, int n_in,
                              void* d_out, int out_size, void* d_ws, size_t ws_size,
                              hipStream_t stream) {
    const int*   cards   = (const int*)  d_in[0];
    const int*   players = (const int*)  d_in[1];
    const int*   deck    = (const int*)  d_in[2];
    const int*   oppd    = (const int*)  d_in[3];
    const float* tok     = (const float*)d_in[4];
    const float* pemb    = (const float*)d_in[5];
    const float* pos     = (const float*)d_in[6];
    const float* ln1s  = (const float*)d_in[9];
    const float* ln1b  = (const float*)d_in[10];
    const float* qkvw  = (const float*)d_in[11];
    const float* qkvb  = (const float*)d_in[12];
    const float* projw = (const float*)d_in[13];
    const float* projb = (const float*)d_in[14];
    const float* ln2s  = (const float*)d_in[15];
    const float* ln2b  = (const float*)d_in[16];
    const float* fc1w  = (const float*)d_in[17];
    const float* fc1b  = (const float*)d_in[18];
    const float* fc2w  = (const float*)d_in[19];
    const float* fc2b  = (const float*)d_in[20];
    const float* lnfs  = (const float*)d_in[21];
    const float* lnfb  = (const float*)d_in[22];
    const float* hw    = (const float*)d_in[23];
    const float* hb    = (const float*)d_in[24];
    float* out = (float*)d_out;

    char* p = (char*)d_ws;
    auto alloc = [&](size_t bytes) { char* q = p; p += (bytes + 255) & ~((size_t)255); return q; };
    float* x     = (float*)alloc(8192ull * 768 * 4);
    bf16*  xn    = (bf16*) alloc(8192ull * 768 * 2);
    bf16*  big   = (bf16*) alloc(8192ull * 3072 * 2);
    bf16*  wt    = (bf16*) alloc(7077888ull * 2);      // all 4 transposed mats of one layer
    float* deckm = (float*)alloc(2ull * 16 * 768 * 4);
    int*   maskb = (int*)  alloc(8192ull * 4);
    int*   lasti = (int*)  alloc(64);

    bf16* wq = wt;                        // [2304][768]
    bf16* wp = wq + 2304ull * 768;        // [768][768]
    bf16* w1 = wp + 768ull * 768;         // [3072][768]
    bf16* w2 = w1 + 3072ull * 768;        // [768][3072]

    deckmean_k<<<dim3(16, 2), 256, 0, stream>>>(deck, oppd, tok, deckm);
    mask_k<<<16, 512, 0, stream>>>(cards, maskb, lasti);
    embed_k<<<8192, 256, 0, stream>>>(cards, players, tok, pemb, pos, deckm, x);

    for (int i = 0; i < 6; i++) {
        transpose4_k<<<6912, dim3(32, 8), 0, stream>>>(
            qkvw + (size_t)i * 768 * 2304, projw + (size_t)i * 768 * 768,
            fc1w + (size_t)i * 768 * 3072, fc2w + (size_t)i * 3072 * 768,
            wq, wp, w1, w2);

        // attention block
        ln_k<<<8192, 256, 0, stream>>>(x, ln1s + i * 768, ln1b + i * 768, xn);
        gemm_k<<<dim3(64 * 18, 1, 1), 256, 0, stream>>>(xn, wq, qkvb + i * 2304, nullptr, nullptr, big,
                                                        2304, 768, 0, 18, 1, 0);
        attn_k<<<dim3(8, 12, 16), 256, 0, stream>>>(big, maskb, xn);
        gemm_k<<<dim3(64 * 6, 1, 2), 256, 0, stream>>>(xn, wp, projb + i * 768, nullptr, x, nullptr,
                                                       768, 768, 0, 6, 2, 1);
        // MLP block
        ln_k<<<8192, 256, 0, stream>>>(x, ln2s + i * 768, ln2b + i * 768, xn);
        gemm_k<<<dim3(64 * 24, 1, 1), 256, 0, stream>>>(xn, w1, fc1b + i * 3072, nullptr, nullptr, big,
                                                        3072, 768, 1, 24, 1, 0);
        gemm_k<<<dim3(64 * 6, 1, 4), 256, 0, stream>>>(big, w2, fc2b + i * 768, nullptr, x, nullptr,
                                                       768, 3072, 0, 6, 4, 1);
    }

    head_k<<<16, 256, 0, stream>>>(x, lasti, lnfs, lnfb, hw, hb, out);
}

// Round 5
// 2186.062 us; speedup vs baseline: 1.2165x; 1.2165x over previous
//
#include <hip/hip_runtime.h>
#include <hip/hip_bf16.h>
#include <math.h>

typedef __hip_bfloat16 bf16;
typedef __bf16 bf16x8 __attribute__((ext_vector_type(8)));
typedef float f32x4 __attribute__((ext_vector_type(4)));

__device__ __forceinline__ float b2f(bf16 v){ return __bfloat162float(v); }
__device__ __forceinline__ bf16  f2b(float v){ return __float2bfloat16(v); }

// async global->LDS, 16B per lane; LDS dest = wave-uniform base + lane*16
__device__ __forceinline__ void gl_lds16(const bf16* g, bf16* l) {
    __builtin_amdgcn_global_load_lds((const __attribute__((address_space(1))) unsigned int*)g,
                                     (__attribute__((address_space(3))) unsigned int*)l, 16, 0, 0);
}

// ---------------- deck means ----------------
__global__ __launch_bounds__(256) void deckmean_k(const int* __restrict__ deck, const int* __restrict__ opp,
                                                  const float* __restrict__ tok, float* __restrict__ deckm)
{
    int b = blockIdx.x, w = blockIdx.y;
    const int* dk = (w ? opp : deck) + b * 8;
    int idx[8];
    #pragma unroll
    for (int j = 0; j < 8; j++) idx[j] = dk[j];
    float* out = deckm + (size_t)(w * 16 + b) * 768;
    for (int d = threadIdx.x; d < 768; d += 256) {
        float s = 0.f;
        #pragma unroll
        for (int j = 0; j < 8; j++) s += tok[(size_t)idx[j] * 768 + d];
        out[d] = s * 0.125f;
    }
}

// ---------------- mask + last_idx ----------------
__global__ __launch_bounds__(512) void mask_k(const int* __restrict__ cards, int* __restrict__ maskb,
                                              int* __restrict__ lastidx)
{
    int b = blockIdx.x, t = threadIdx.x;
    int m = (cards[b * 512 + t] != 0) ? 1 : 0;
    maskb[b * 512 + t] = m;
    __shared__ int red[512];
    red[t] = m; __syncthreads();
    for (int st = 256; st > 0; st >>= 1) { if (t < st) red[t] += red[t + st]; __syncthreads(); }
    if (t == 0) {
        int cnt = red[0];
        if (cnt == 0) { maskb[b * 512] = 1; cnt = 1; }  // all-pad fix
        lastidx[b] = cnt - 1;
    }
}

// ---------------- embedding sum -> fp32 residual stream ----------------
__global__ __launch_bounds__(256) void embed_k(const int* __restrict__ cards, const int* __restrict__ players,
                                               const float* __restrict__ tok, const float* __restrict__ pemb,
                                               const float* __restrict__ pos, const float* __restrict__ deckm,
                                               float* __restrict__ x)
{
    int t = blockIdx.x;
    int b = t >> 9, ti = t & 511;
    int cd = cards[t];
    int p = players[t]; p = p < 0 ? 0 : (p > 1 ? 1 : p);
    const float* tr  = tok  + (size_t)cd * 768;
    const float* pr  = pemb + (size_t)p  * 768;
    const float* po  = pos  + (size_t)ti * 768;
    const float* dm = deckm + (size_t)b * 768;
    const float* om = deckm + (size_t)(16 + b) * 768;
    float* xr = x + (size_t)t * 768;
    for (int d = threadIdx.x; d < 768; d += 256)
        xr[d] = tr[d] + pr[d] + po[d] + dm[d] + om[d];
}

// ---------------- layernorm: fp32 in -> bf16 out ----------------
__global__ __launch_bounds__(256) void ln_k(const float* __restrict__ x, const float* __restrict__ s,
                                            const float* __restrict__ b, bf16* __restrict__ out)
{
    int row = blockIdx.x, tid = threadIdx.x;
    const float* xr = x + (size_t)row * 768;
    float v0 = xr[tid], v1 = xr[tid + 256], v2 = xr[tid + 512];
    __shared__ float rs[256], rq[256];
    rs[tid] = v0 + v1 + v2; rq[tid] = v0 * v0 + v1 * v1 + v2 * v2;
    __syncthreads();
    for (int st = 128; st > 0; st >>= 1) {
        if (tid < st) { rs[tid] += rs[tid + st]; rq[tid] += rq[tid + st]; }
        __syncthreads();
    }
    float mean = rs[0] * (1.f / 768.f);
    float var  = rq[0] * (1.f / 768.f) - mean * mean;
    float rstd = rsqrtf(var + 1e-5f);
    bf16* orow = out + (size_t)row * 768;
    orow[tid]       = f2b((v0 - mean) * rstd * s[tid]       + b[tid]);
    orow[tid + 256] = f2b((v1 - mean) * rstd * s[tid + 256] + b[tid + 256]);
    orow[tid + 512] = f2b((v2 - mean) * rstd * s[tid + 512] + b[tid + 512]);
}

// ---------------- batched 32x32 transpose+downcast of one layer's 4 weight mats ----------------
__global__ void transpose4_k(const float* __restrict__ qw, const float* __restrict__ pw,
                             const float* __restrict__ f1, const float* __restrict__ f2,
                             bf16* __restrict__ oq, bf16* __restrict__ op,
                             bf16* __restrict__ o1, bf16* __restrict__ o2)
{
    int t = blockIdx.x;
    const float* in; bf16* out; int K, N, nbx;
    if (t < 1728)      { in = qw; out = oq; K = 768;  N = 2304; nbx = 72; }
    else if (t < 2304) { in = pw; out = op; K = 768;  N = 768;  t -= 1728; nbx = 24; }
    else if (t < 4608) { in = f1; out = o1; K = 768;  N = 3072; t -= 2304; nbx = 96; }
    else               { in = f2; out = o2; K = 3072; N = 768;  t -= 4608; nbx = 24; }
    int n0 = (t % nbx) * 32, k0 = (t / nbx) * 32;
    __shared__ bf16 tl[32][33];
    int tx = threadIdx.x, ty = threadIdx.y;
    #pragma unroll
    for (int i = 0; i < 32; i += 8)
        tl[ty + i][tx] = f2b(in[(size_t)(k0 + ty + i) * N + n0 + tx]);
    __syncthreads();
    #pragma unroll
    for (int i = 0; i < 32; i += 8)
        out[(size_t)(n0 + ty + i) * K + k0 + tx] = tl[tx][ty + i];
}

// ---------------- MFMA GEMM 128x128 (m97 staging + XCD swizzle): wide-N GEMMs (qkv, fc1) ----------
// grid = 8*8*nb blocks (64 m-tiles). xcd = bid&7 owns 8 contiguous m-stripes; n fastest.
__global__ __launch_bounds__(256) void gemm128_k(const bf16* __restrict__ A, const bf16* __restrict__ BT,
                                                 const float* __restrict__ bias,
                                                 float* __restrict__ outF, bf16* __restrict__ outB,
                                                 int N, int K, int act, int nb)
{
    __shared__ __align__(16) bf16 Al[128 * 64];
    __shared__ __align__(16) bf16 Bl[128 * 64];
    const int tid = threadIdx.x;
    const int lane = tid & 63, wave = tid >> 6;
    const int quad = lane >> 4, l16 = lane & 15;
    const int wm = wave >> 1, wn = wave & 1;

    const int bid = blockIdx.x;
    const int xcd = bid & 7, slot = bid >> 3;
    const int m_loc = slot / nb, nbl = slot - m_loc * nb;
    const int m0 = (xcd * 8 + m_loc) * 128, n0 = nbl * 128;

    f32x4 acc[4][4] = {};
    const int srow = wave * 32;
    const int grow = srow + (lane >> 3);
    const int gcol = (lane & 7) * 8;

    for (int k0 = 0; k0 < K; k0 += 64) {
        #pragma unroll
        for (int i = 0; i < 4; i++) {
            gl_lds16(&A [(size_t)(m0 + grow + i * 8) * K + k0 + gcol], &Al[(srow + i * 8) * 64]);
            gl_lds16(&BT[(size_t)(n0 + grow + i * 8) * K + k0 + gcol], &Bl[(srow + i * 8) * 64]);
        }
        __syncthreads();
        #pragma unroll
        for (int kk = 0; kk < 64; kk += 32) {
            bf16x8 af[4], bfr[4];
            #pragma unroll
            for (int t = 0; t < 4; t++) {
                af[t]  = __builtin_bit_cast(bf16x8, *(const uint4*)(&Al[(wm * 64 + t * 16 + l16) * 64 + kk + quad * 8]));
                bfr[t] = __builtin_bit_cast(bf16x8, *(const uint4*)(&Bl[(wn * 64 + t * 16 + l16) * 64 + kk + quad * 8]));
            }
            #pragma unroll
            for (int tm = 0; tm < 4; tm++)
                #pragma unroll
                for (int tn = 0; tn < 4; tn++)
                    acc[tm][tn] = __builtin_amdgcn_mfma_f32_16x16x32_bf16(af[tm], bfr[tn], acc[tm][tn], 0, 0, 0);
        }
        __syncthreads();
    }

    float bv[4];
    #pragma unroll
    for (int tn = 0; tn < 4; tn++)
        bv[tn] = bias[n0 + wn * 64 + tn * 16 + l16];

    #pragma unroll
    for (int tm = 0; tm < 4; tm++) {
        #pragma unroll
        for (int tn = 0; tn < 4; tn++) {
            int n = n0 + wn * 64 + tn * 16 + l16;
            #pragma unroll
            for (int r = 0; r < 4; r++) {
                int m = m0 + wm * 64 + tm * 16 + quad * 4 + r;   // C/D: col=lane&15, row=quad*4+reg
                float v = acc[tm][tn][r] + bv[tn];
                if (act) v = 0.5f * v * (1.0f + erff(v * 0.70710678118654752f));
                size_t off = (size_t)m * N + n;
                if (outB) outB[off] = f2b(v);
                else      outF[off] = v;
            }
        }
    }
}

// ---------------- MFMA GEMM 64x128 (narrow-N: proj, fc2): fused fp32 residual add into x -------
// tile M=64 N=128, 4 waves 2x2 (each 32x64 = 2x4 mfma). grid = 8*16*nb. 24KB LDS -> high occupancy.
__global__ __launch_bounds__(256) void gemm64_k(const bf16* __restrict__ A, const bf16* __restrict__ BT,
                                                const float* __restrict__ bias,
                                                float* __restrict__ x, int N, int K, int nb)
{
    __shared__ __align__(16) bf16 Al[64 * 64];
    __shared__ __align__(16) bf16 Bl[128 * 64];
    const int tid = threadIdx.x;
    const int lane = tid & 63, wave = tid >> 6;
    const int quad = lane >> 4, l16 = lane & 15;
    const int wm = wave >> 1, wn = wave & 1;

    const int bid = blockIdx.x;
    const int xcd = bid & 7, slot = bid >> 3;
    const int m_loc = slot / nb, nbl = slot - m_loc * nb;
    const int m0 = (xcd * 16 + m_loc) * 64, n0 = nbl * 128;

    f32x4 acc[2][4] = {};
    const int srow = wave * 8 + (lane >> 3);
    const int gcol = (lane & 7) * 8;

    for (int k0 = 0; k0 < K; k0 += 64) {
        #pragma unroll
        for (int i = 0; i < 2; i++)
            gl_lds16(&A [(size_t)(m0 + srow + i * 32) * K + k0 + gcol], &Al[(wave * 8 + i * 32) * 64]);
        #pragma unroll
        for (int i = 0; i < 4; i++)
            gl_lds16(&BT[(size_t)(n0 + srow + i * 32) * K + k0 + gcol], &Bl[(wave * 8 + i * 32) * 64]);
        __syncthreads();
        #pragma unroll
        for (int kk = 0; kk < 64; kk += 32) {
            bf16x8 af[2], bfr[4];
            #pragma unroll
            for (int t = 0; t < 2; t++)
                af[t]  = __builtin_bit_cast(bf16x8, *(const uint4*)(&Al[(wm * 32 + t * 16 + l16) * 64 + kk + quad * 8]));
            #pragma unroll
            for (int t = 0; t < 4; t++)
                bfr[t] = __builtin_bit_cast(bf16x8, *(const uint4*)(&Bl[(wn * 64 + t * 16 + l16) * 64 + kk + quad * 8]));
            #pragma unroll
            for (int tm = 0; tm < 2; tm++)
                #pragma unroll
                for (int tn = 0; tn < 4; tn++)
                    acc[tm][tn] = __builtin_amdgcn_mfma_f32_16x16x32_bf16(af[tm], bfr[tn], acc[tm][tn], 0, 0, 0);
        }
        __syncthreads();
    }

    float bv[4];
    #pragma unroll
    for (int tn = 0; tn < 4; tn++)
        bv[tn] = bias[n0 + wn * 64 + tn * 16 + l16];

    #pragma unroll
    for (int tm = 0; tm < 2; tm++) {
        #pragma unroll
        for (int tn = 0; tn < 4; tn++) {
            int n = n0 + wn * 64 + tn * 16 + l16;
            #pragma unroll
            for (int r = 0; r < 4; r++) {
                int m = m0 + wm * 32 + tm * 16 + quad * 4 + r;
                size_t off = (size_t)m * N + n;
                x[off] += acc[tm][tn][r] + bv[tn];   // fused residual (splitK=1: no race)
            }
        }
    }
}

// ---------------- MFMA flash attention ----------------
__global__ __launch_bounds__(256) void attn_k(const bf16* __restrict__ qkv, const int* __restrict__ mask,
                                              bf16* __restrict__ y)
{
    const int qt = blockIdx.x, h = blockIdx.y, b = blockIdx.z;
    const int qbase = qt * 64, tokb = b * 512;
    __shared__ __align__(16) unsigned short Kl[128][72];
    __shared__ __align__(16) unsigned short Vt[64][136];
    __shared__ __align__(16) unsigned short Ql[64][72];
    __shared__ __align__(16) unsigned short Ptq[4][16][136];
    __shared__ float mkf[128];

    const int tid = threadIdx.x, wave = tid >> 6, lane = tid & 63;
    const int quad = lane >> 4, l16 = lane & 15;
    const int qi = qbase + wave * 16 + l16;

    {
        int row = tid >> 2, c0 = (tid & 3) * 16;
        const bf16* g = &qkv[(size_t)(tokb + qbase + row) * 2304 + h * 64 + c0];
        *(uint4*)&Ql[row][c0]     = *(const uint4*)(g);
        *(uint4*)&Ql[row][c0 + 8] = *(const uint4*)(g + 8);
    }
    __syncthreads();
    bf16x8 bq[2];
    bq[0] = __builtin_bit_cast(bf16x8, *(const uint4*)&Ql[wave * 16 + l16][quad * 8]);
    bq[1] = __builtin_bit_cast(bf16x8, *(const uint4*)&Ql[wave * 16 + l16][32 + quad * 8]);

    float m_i = -INFINITY, l_i = 0.f;
    f32x4 Oacc[4] = {};

    const int nst = (qbase >> 7) + 1;
    for (int s = 0; s < nst; s++) {
        const int j0 = s * 128;
        __syncthreads();
        {
            int key = tid >> 1, c0 = (tid & 1) * 32;
            const bf16* kg = &qkv[(size_t)(tokb + j0 + key) * 2304 + 768  + h * 64 + c0];
            const bf16* vg = &qkv[(size_t)(tokb + j0 + key) * 2304 + 1536 + h * 64 + c0];
            #pragma unroll
            for (int q = 0; q < 4; q++)
                *(uint4*)&Kl[key][c0 + q * 8] = *(const uint4*)(kg + q * 8);
            union { uint4 u[4]; unsigned short e[32]; } vv;
            #pragma unroll
            for (int q = 0; q < 4; q++) vv.u[q] = *(const uint4*)(vg + q * 8);
            #pragma unroll
            for (int j = 0; j < 32; j++) Vt[c0 + j][key] = vv.e[j];
            if (tid < 128) mkf[tid] = mask[b * 512 + j0 + tid] ? 0.f : -INFINITY;
        }
        __syncthreads();

        f32x4 sc[8] = {};
        #pragma unroll
        for (int kcc = 0; kcc < 8; kcc++) {
            bf16x8 af0 = __builtin_bit_cast(bf16x8, *(const uint4*)&Kl[kcc * 16 + l16][quad * 8]);
            bf16x8 af1 = __builtin_bit_cast(bf16x8, *(const uint4*)&Kl[kcc * 16 + l16][32 + quad * 8]);
            sc[kcc] = __builtin_amdgcn_mfma_f32_16x16x32_bf16(af0, bq[0], sc[kcc], 0, 0, 0);
            sc[kcc] = __builtin_amdgcn_mfma_f32_16x16x32_bf16(af1, bq[1], sc[kcc], 0, 0, 0);
        }

        float pv[8][4];
        float mx = -INFINITY;
        #pragma unroll
        for (int kcc = 0; kcc < 8; kcc++) {
            float4 mk4 = *(const float4*)&mkf[kcc * 16 + quad * 4];
            float mkr[4] = { mk4.x, mk4.y, mk4.z, mk4.w };
            #pragma unroll
            for (int r = 0; r < 4; r++) {
                int krel = kcc * 16 + quad * 4 + r;
                float sval = (j0 + krel <= qi) ? (sc[kcc][r] * 0.125f + mkr[r]) : -INFINITY;
                pv[kcc][r] = sval;
                mx = fmaxf(mx, sval);
            }
        }
        mx = fmaxf(mx, __shfl_xor(mx, 16, 64));
        mx = fmaxf(mx, __shfl_xor(mx, 32, 64));
        float mn = fmaxf(m_i, mx);
        float alpha = (mn == -INFINITY) ? 1.f : __expf(m_i - mn);
        float lsum = 0.f;
        #pragma unroll
        for (int kcc = 0; kcc < 8; kcc++)
            #pragma unroll
            for (int r = 0; r < 4; r++) {
                float pp = (pv[kcc][r] == -INFINITY) ? 0.f : __expf(pv[kcc][r] - mn);
                pv[kcc][r] = pp; lsum += pp;
            }
        lsum += __shfl_xor(lsum, 16, 64);
        lsum += __shfl_xor(lsum, 32, 64);
        m_i = mn; l_i = alpha * l_i + lsum;

        #pragma unroll
        for (int kcc = 0; kcc < 8; kcc++) {
            union { unsigned short e[4]; uint2 u; } pk;
            #pragma unroll
            for (int r = 0; r < 4; r++) pk.e[r] = __builtin_bit_cast(unsigned short, f2b(pv[kcc][r]));
            *(uint2*)&Ptq[wave][l16][kcc * 16 + quad * 4] = pk.u;
        }
        #pragma unroll
        for (int mc = 0; mc < 4; mc++)
            #pragma unroll
            for (int r = 0; r < 4; r++) Oacc[mc][r] *= alpha;

        __syncthreads();

        #pragma unroll
        for (int kcc = 0; kcc < 4; kcc++) {
            bf16x8 pb = __builtin_bit_cast(bf16x8, *(const uint4*)&Ptq[wave][l16][kcc * 32 + quad * 8]);
            #pragma unroll
            for (int mc = 0; mc < 4; mc++) {
                bf16x8 vf = __builtin_bit_cast(bf16x8, *(const uint4*)&Vt[mc * 16 + l16][kcc * 32 + quad * 8]);
                Oacc[mc] = __builtin_amdgcn_mfma_f32_16x16x32_bf16(vf, pb, Oacc[mc], 0, 0, 0);
            }
        }
    }

    float inv = (l_i > 0.f) ? 1.f / l_i : 0.f;
    const int tok = tokb + qbase + wave * 16 + l16;
    #pragma unroll
    for (int mc = 0; mc < 4; mc++)
        #pragma unroll
        for (int r = 0; r < 4; r++)
            y[(size_t)tok * 768 + h * 64 + mc * 16 + quad * 4 + r] = f2b(Oacc[mc][r] * inv);
}

// ---------------- final LN + last-token select + head (fp32) ----------------
__global__ __launch_bounds__(256) void head_k(const float* __restrict__ x, const int* __restrict__ lastidx,
                                              const float* __restrict__ ls, const float* __restrict__ lb,
                                              const float* __restrict__ hw, const float* __restrict__ hb,
                                              float* __restrict__ out)
{
    int b = blockIdx.x, tid = threadIdx.x;
    const float* xr = x + ((size_t)(b * 512 + lastidx[b])) * 768;
    float v0 = xr[tid], v1 = xr[tid + 256], v2 = xr[tid + 512];
    __shared__ float rs[256], rq[256];
    rs[tid] = v0 + v1 + v2; rq[tid] = v0 * v0 + v1 * v1 + v2 * v2;
    __syncthreads();
    for (int st = 128; st > 0; st >>= 1) {
        if (tid < st) { rs[tid] += rs[tid + st]; rq[tid] += rq[tid + st]; }
        __syncthreads();
    }
    float mean = rs[0] * (1.f / 768.f);
    float var  = rq[0] * (1.f / 768.f) - mean * mean;
    float rstd = rsqrtf(var + 1e-5f);
    float part[9];
    #pragma unroll
    for (int a = 0; a < 9; a++) part[a] = 0.f;
    float vv[3] = { v0, v1, v2 };
    #pragma unroll
    for (int e = 0; e < 3; e++) {
        int d = tid + e * 256;
        float xnv = (vv[e] - mean) * rstd * ls[d] + lb[d];
        #pragma unroll
        for (int a = 0; a < 9; a++) part[a] += xnv * hw[d * 9 + a];
    }
    __shared__ float r9[9][256];
    #pragma unroll
    for (int a = 0; a < 9; a++) r9[a][tid] = part[a];
    __syncthreads();
    for (int st = 128; st > 0; st >>= 1) {
        if (tid < st) {
            for (int a = 0; a < 9; a++) r9[a][tid] += r9[a][tid + st];
        }
        __syncthreads();
    }
    if (tid < 9) out[b * 9 + tid] = r9[tid][0] + hb[tid];
}

extern "C" void kernel_launch(void* const* d_in, const int* in_sizes, int n_in,
                              void* d_out, int out_size, void* d_ws, size_t ws_size,
                              hipStream_t stream) {
    const int*   cards   = (const int*)  d_in[0];
    const int*   players = (const int*)  d_in[1];
    const int*   deck    = (const int*)  d_in[2];
    const int*   oppd    = (const int*)  d_in[3];
    const float* tok     = (const float*)d_in[4];
    const float* pemb    = (const float*)d_in[5];
    const float* pos     = (const float*)d_in[6];
    const float* ln1s  = (const float*)d_in[9];
    const float* ln1b  = (const float*)d_in[10];
    const float* qkvw  = (const float*)d_in[11];
    const float* qkvb  = (const float*)d_in[12];
    const float* projw = (const float*)d_in[13];
    const float* projb = (const float*)d_in[14];
    const float* ln2s  = (const float*)d_in[15];
    const float* ln2b  = (const float*)d_in[16];
    const float* fc1w  = (const float*)d_in[17];
    const float* fc1b  = (const float*)d_in[18];
    const float* fc2w  = (const float*)d_in[19];
    const float* fc2b  = (const float*)d_in[20];
    const float* lnfs  = (const float*)d_in[21];
    const float* lnfb  = (const float*)d_in[22];
    const float* hw    = (const float*)d_in[23];
    const float* hb    = (const float*)d_in[24];
    float* out = (float*)d_out;

    char* p = (char*)d_ws;
    auto alloc = [&](size_t bytes) { char* q = p; p += (bytes + 255) & ~((size_t)255); return q; };
    float* x     = (float*)alloc(8192ull * 768 * 4);
    bf16*  xn    = (bf16*) alloc(8192ull * 768 * 2);
    bf16*  big   = (bf16*) alloc(8192ull * 3072 * 2);
    bf16*  wt    = (bf16*) alloc(7077888ull * 2);      // all 4 transposed mats of one layer
    float* deckm = (float*)alloc(2ull * 16 * 768 * 4);
    int*   maskb = (int*)  alloc(8192ull * 4);
    int*   lasti = (int*)  alloc(64);

    bf16* wq = wt;                        // [2304][768]
    bf16* wp = wq + 2304ull * 768;        // [768][768]
    bf16* w1 = wp + 768ull * 768;         // [3072][768]
    bf16* w2 = w1 + 3072ull * 768;        // [768][3072]

    deckmean_k<<<dim3(16, 2), 256, 0, stream>>>(deck, oppd, tok, deckm);
    mask_k<<<16, 512, 0, stream>>>(cards, maskb, lasti);
    embed_k<<<8192, 256, 0, stream>>>(cards, players, tok, pemb, pos, deckm, x);

    for (int i = 0; i < 6; i++) {
        transpose4_k<<<6912, dim3(32, 8), 0, stream>>>(
            qkvw + (size_t)i * 768 * 2304, projw + (size_t)i * 768 * 768,
            fc1w + (size_t)i * 768 * 3072, fc2w + (size_t)i * 3072 * 768,
            wq, wp, w1, w2);

        // attention block
        ln_k<<<8192, 256, 0, stream>>>(x, ln1s + i * 768, ln1b + i * 768, xn);
        gemm128_k<<<64 * 18, 256, 0, stream>>>(xn, wq, qkvb + i * 2304, nullptr, big, 2304, 768, 0, 18);
        attn_k<<<dim3(8, 12, 16), 256, 0, stream>>>(big, maskb, xn);
        gemm64_k<<<128 * 6, 256, 0, stream>>>(xn, wp, projb + i * 768, x, 768, 768, 6);
        // MLP block
        ln_k<<<8192, 256, 0, stream>>>(x, ln2s + i * 768, ln2b + i * 768, xn);
        gemm128_k<<<64 * 24, 256, 0, stream>>>(xn, w1, fc1b + i * 3072, nullptr, big, 3072, 768, 1, 24);
        gemm64_k<<<128 * 6, 256, 0, stream>>>(big, w2, fc2b + i * 768, x, 768, 3072, 6);
    }

    head_k<<<16, 256, 0, stream>>>(x, lasti, lnfs, lnfb, hw, hb, out);
}

// Round 6
// 2110.155 us; speedup vs baseline: 1.2603x; 1.0360x over previous
//
#include <hip/hip_runtime.h>
#include <hip/hip_bf16.h>
#include <math.h>

typedef __hip_bfloat16 bf16;
typedef __bf16 bf16x8 __attribute__((ext_vector_type(8)));
typedef float f32x4 __attribute__((ext_vector_type(4)));

__device__ __forceinline__ float b2f(bf16 v){ return __bfloat162float(v); }
__device__ __forceinline__ bf16  f2b(float v){ return __float2bfloat16(v); }

// tanh-form gelu: 0.5v(1+tanh(0.79788456(v+0.044715v^3))) = v*sigmoid(1.59577(v+0.044715v^3))
// max |diff vs exact erf-gelu| ~1e-3; ~6 VALU ops vs ~30 for erff.
__device__ __forceinline__ float gelu_f(float v){
    float y = v * (1.f + 0.044715f * v * v);
    return v / (1.f + __expf(-1.5957691216057308f * y));
}

// async global->LDS, 16B per lane; LDS dest = wave-uniform base + lane*16
__device__ __forceinline__ void gl_lds16(const bf16* g, bf16* l) {
    __builtin_amdgcn_global_load_lds((const __attribute__((address_space(1))) unsigned int*)g,
                                     (__attribute__((address_space(3))) unsigned int*)l, 16, 0, 0);
}

__device__ __forceinline__ uint2 pack4bf(const float* v){
    union { unsigned short e[4]; uint2 u; } pk;
    #pragma unroll
    for (int r = 0; r < 4; r++) pk.e[r] = __builtin_bit_cast(unsigned short, f2b(v[r]));
    return pk.u;
}

// ---------------- deck means ----------------
__global__ __launch_bounds__(256) void deckmean_k(const int* __restrict__ deck, const int* __restrict__ opp,
                                                  const float* __restrict__ tok, float* __restrict__ deckm)
{
    int b = blockIdx.x, w = blockIdx.y;
    const int* dk = (w ? opp : deck) + b * 8;
    int idx[8];
    #pragma unroll
    for (int j = 0; j < 8; j++) idx[j] = dk[j];
    float* out = deckm + (size_t)(w * 16 + b) * 768;
    for (int d = threadIdx.x; d < 768; d += 256) {
        float s = 0.f;
        #pragma unroll
        for (int j = 0; j < 8; j++) s += tok[(size_t)idx[j] * 768 + d];
        out[d] = s * 0.125f;
    }
}

// ---------------- mask + last_idx ----------------
__global__ __launch_bounds__(512) void mask_k(const int* __restrict__ cards, int* __restrict__ maskb,
                                              int* __restrict__ lastidx)
{
    int b = blockIdx.x, t = threadIdx.x;
    int m = (cards[b * 512 + t] != 0) ? 1 : 0;
    maskb[b * 512 + t] = m;
    __shared__ int red[512];
    red[t] = m; __syncthreads();
    for (int st = 256; st > 0; st >>= 1) { if (t < st) red[t] += red[t + st]; __syncthreads(); }
    if (t == 0) {
        int cnt = red[0];
        if (cnt == 0) { maskb[b * 512] = 1; cnt = 1; }  // all-pad fix
        lastidx[b] = cnt - 1;
    }
}

// ---------------- embedding sum -> fp32 residual stream ----------------
__global__ __launch_bounds__(256) void embed_k(const int* __restrict__ cards, const int* __restrict__ players,
                                               const float* __restrict__ tok, const float* __restrict__ pemb,
                                               const float* __restrict__ pos, const float* __restrict__ deckm,
                                               float* __restrict__ x)
{
    int t = blockIdx.x;
    int b = t >> 9, ti = t & 511;
    int cd = cards[t];
    int p = players[t]; p = p < 0 ? 0 : (p > 1 ? 1 : p);
    const float* tr  = tok  + (size_t)cd * 768;
    const float* pr  = pemb + (size_t)p  * 768;
    const float* po  = pos  + (size_t)ti * 768;
    const float* dm = deckm + (size_t)b * 768;
    const float* om = deckm + (size_t)(16 + b) * 768;
    float* xr = x + (size_t)t * 768;
    for (int d = threadIdx.x; d < 768; d += 256)
        xr[d] = tr[d] + pr[d] + po[d] + dm[d] + om[d];
}

// ---------------- layernorm: fp32 in -> bf16 out ----------------
__global__ __launch_bounds__(256) void ln_k(const float* __restrict__ x, const float* __restrict__ s,
                                            const float* __restrict__ b, bf16* __restrict__ out)
{
    int row = blockIdx.x, tid = threadIdx.x;
    const float* xr = x + (size_t)row * 768;
    float v0 = xr[tid], v1 = xr[tid + 256], v2 = xr[tid + 512];
    __shared__ float rs[256], rq[256];
    rs[tid] = v0 + v1 + v2; rq[tid] = v0 * v0 + v1 * v1 + v2 * v2;
    __syncthreads();
    for (int st = 128; st > 0; st >>= 1) {
        if (tid < st) { rs[tid] += rs[tid + st]; rq[tid] += rq[tid + st]; }
        __syncthreads();
    }
    float mean = rs[0] * (1.f / 768.f);
    float var  = rq[0] * (1.f / 768.f) - mean * mean;
    float rstd = rsqrtf(var + 1e-5f);
    bf16* orow = out + (size_t)row * 768;
    orow[tid]       = f2b((v0 - mean) * rstd * s[tid]       + b[tid]);
    orow[tid + 256] = f2b((v1 - mean) * rstd * s[tid + 256] + b[tid + 256]);
    orow[tid + 512] = f2b((v2 - mean) * rstd * s[tid + 512] + b[tid + 512]);
}

// ---------------- batched 32x32 transpose+downcast of one layer's 4 weight mats ----------------
__global__ void transpose4_k(const float* __restrict__ qw, const float* __restrict__ pw,
                             const float* __restrict__ f1, const float* __restrict__ f2,
                             bf16* __restrict__ oq, bf16* __restrict__ op,
                             bf16* __restrict__ o1, bf16* __restrict__ o2)
{
    int t = blockIdx.x;
    const float* in; bf16* out; int K, N, nbx;
    if (t < 1728)      { in = qw; out = oq; K = 768;  N = 2304; nbx = 72; }
    else if (t < 2304) { in = pw; out = op; K = 768;  N = 768;  t -= 1728; nbx = 24; }
    else if (t < 4608) { in = f1; out = o1; K = 768;  N = 3072; t -= 2304; nbx = 96; }
    else               { in = f2; out = o2; K = 3072; N = 768;  t -= 4608; nbx = 24; }
    int n0 = (t % nbx) * 32, k0 = (t / nbx) * 32;
    __shared__ bf16 tl[32][33];
    int tx = threadIdx.x, ty = threadIdx.y;
    #pragma unroll
    for (int i = 0; i < 32; i += 8)
        tl[ty + i][tx] = f2b(in[(size_t)(k0 + ty + i) * N + n0 + tx]);
    __syncthreads();
    #pragma unroll
    for (int i = 0; i < 32; i += 8)
        out[(size_t)(n0 + ty + i) * K + k0 + tx] = tl[tx][ty + i];
}

// ---------------- MFMA GEMM 128x128 (m97 staging + XCD swizzle), swapped operands ----------------
// acc holds D^T: col(l16)=m-within-tile, row(quad*4+r)=n-within-tile -> packed uint2/float4 stores.
__global__ __launch_bounds__(256) void gemm128_k(const bf16* __restrict__ A, const bf16* __restrict__ BT,
                                                 const float* __restrict__ bias,
                                                 float* __restrict__ outF, bf16* __restrict__ outB,
                                                 int N, int K, int act, int nb)
{
    __shared__ __align__(16) bf16 Al[128 * 64];
    __shared__ __align__(16) bf16 Bl[128 * 64];
    const int tid = threadIdx.x;
    const int lane = tid & 63, wave = tid >> 6;
    const int quad = lane >> 4, l16 = lane & 15;
    const int wm = wave >> 1, wn = wave & 1;

    const int bid = blockIdx.x;
    const int xcd = bid & 7, slot = bid >> 3;
    const int m_loc = slot / nb, nbl = slot - m_loc * nb;
    const int m0 = (xcd * 8 + m_loc) * 128, n0 = nbl * 128;

    f32x4 acc[4][4] = {};
    const int srow = wave * 32;
    const int grow = srow + (lane >> 3);
    const int gcol = (lane & 7) * 8;

    for (int k0 = 0; k0 < K; k0 += 64) {
        #pragma unroll
        for (int i = 0; i < 4; i++) {
            gl_lds16(&A [(size_t)(m0 + grow + i * 8) * K + k0 + gcol], &Al[(srow + i * 8) * 64]);
            gl_lds16(&BT[(size_t)(n0 + grow + i * 8) * K + k0 + gcol], &Bl[(srow + i * 8) * 64]);
        }
        __syncthreads();
        #pragma unroll
        for (int kk = 0; kk < 64; kk += 32) {
            bf16x8 af[4], bfr[4];
            #pragma unroll
            for (int t = 0; t < 4; t++) {
                af[t]  = __builtin_bit_cast(bf16x8, *(const uint4*)(&Al[(wm * 64 + t * 16 + l16) * 64 + kk + quad * 8]));
                bfr[t] = __builtin_bit_cast(bf16x8, *(const uint4*)(&Bl[(wn * 64 + t * 16 + l16) * 64 + kk + quad * 8]));
            }
            #pragma unroll
            for (int tm = 0; tm < 4; tm++)
                #pragma unroll
                for (int tn = 0; tn < 4; tn++)
                    acc[tm][tn] = __builtin_amdgcn_mfma_f32_16x16x32_bf16(bfr[tn], af[tm], acc[tm][tn], 0, 0, 0);
        }
        __syncthreads();
    }

    float4 bv[4];
    #pragma unroll
    for (int tn = 0; tn < 4; tn++)
        bv[tn] = *(const float4*)&bias[n0 + wn * 64 + tn * 16 + quad * 4];

    #pragma unroll
    for (int tm = 0; tm < 4; tm++) {
        int m = m0 + wm * 64 + tm * 16 + l16;
        #pragma unroll
        for (int tn = 0; tn < 4; tn++) {
            int nbase = n0 + wn * 64 + tn * 16 + quad * 4;
            float v[4] = { acc[tm][tn][0] + bv[tn].x, acc[tm][tn][1] + bv[tn].y,
                           acc[tm][tn][2] + bv[tn].z, acc[tm][tn][3] + bv[tn].w };
            if (act) {
                #pragma unroll
                for (int r = 0; r < 4; r++) v[r] = gelu_f(v[r]);
            }
            size_t off = (size_t)m * N + nbase;
            if (outB) *(uint2*)&outB[off] = pack4bf(v);
            else      *(float4*)&outF[off] = make_float4(v[0], v[1], v[2], v[3]);
        }
    }
}

// ---------------- MFMA GEMM 64x128 (narrow-N: proj, fc2), swapped operands + float4 residual RMW -
__global__ __launch_bounds__(256) void gemm64_k(const bf16* __restrict__ A, const bf16* __restrict__ BT,
                                                const float* __restrict__ bias,
                                                float* __restrict__ x, int N, int K, int nb)
{
    __shared__ __align__(16) bf16 Al[64 * 64];
    __shared__ __align__(16) bf16 Bl[128 * 64];
    const int tid = threadIdx.x;
    const int lane = tid & 63, wave = tid >> 6;
    const int quad = lane >> 4, l16 = lane & 15;
    const int wm = wave >> 1, wn = wave & 1;

    const int bid = blockIdx.x;
    const int xcd = bid & 7, slot = bid >> 3;
    const int m_loc = slot / nb, nbl = slot - m_loc * nb;
    const int m0 = (xcd * 16 + m_loc) * 64, n0 = nbl * 128;

    f32x4 acc[2][4] = {};
    const int srow = wave * 8 + (lane >> 3);
    const int gcol = (lane & 7) * 8;

    for (int k0 = 0; k0 < K; k0 += 64) {
        #pragma unroll
        for (int i = 0; i < 2; i++)
            gl_lds16(&A [(size_t)(m0 + srow + i * 32) * K + k0 + gcol], &Al[(wave * 8 + i * 32) * 64]);
        #pragma unroll
        for (int i = 0; i < 4; i++)
            gl_lds16(&BT[(size_t)(n0 + srow + i * 32) * K + k0 + gcol], &Bl[(wave * 8 + i * 32) * 64]);
        __syncthreads();
        #pragma unroll
        for (int kk = 0; kk < 64; kk += 32) {
            bf16x8 af[2], bfr[4];
            #pragma unroll
            for (int t = 0; t < 2; t++)
                af[t]  = __builtin_bit_cast(bf16x8, *(const uint4*)(&Al[(wm * 32 + t * 16 + l16) * 64 + kk + quad * 8]));
            #pragma unroll
            for (int t = 0; t < 4; t++)
                bfr[t] = __builtin_bit_cast(bf16x8, *(const uint4*)(&Bl[(wn * 64 + t * 16 + l16) * 64 + kk + quad * 8]));
            #pragma unroll
            for (int tm = 0; tm < 2; tm++)
                #pragma unroll
                for (int tn = 0; tn < 4; tn++)
                    acc[tm][tn] = __builtin_amdgcn_mfma_f32_16x16x32_bf16(bfr[tn], af[tm], acc[tm][tn], 0, 0, 0);
        }
        __syncthreads();
    }

    float4 bv[4];
    #pragma unroll
    for (int tn = 0; tn < 4; tn++)
        bv[tn] = *(const float4*)&bias[n0 + wn * 64 + tn * 16 + quad * 4];

    #pragma unroll
    for (int tm = 0; tm < 2; tm++) {
        int m = m0 + wm * 32 + tm * 16 + l16;
        #pragma unroll
        for (int tn = 0; tn < 4; tn++) {
            int nbase = n0 + wn * 64 + tn * 16 + quad * 4;
            float* xp = &x[(size_t)m * N + nbase];
            float4 xo = *(float4*)xp;
            xo.x += acc[tm][tn][0] + bv[tn].x;
            xo.y += acc[tm][tn][1] + bv[tn].y;
            xo.z += acc[tm][tn][2] + bv[tn].z;
            xo.w += acc[tm][tn][3] + bv[tn].w;
            *(float4*)xp = xo;      // splitK=1: no race
        }
    }
}

// ---------------- MFMA flash attention ----------------
__global__ __launch_bounds__(256) void attn_k(const bf16* __restrict__ qkv, const int* __restrict__ mask,
                                              bf16* __restrict__ y)
{
    const int qt = blockIdx.x, h = blockIdx.y, b = blockIdx.z;
    const int qbase = qt * 64, tokb = b * 512;
    __shared__ __align__(16) unsigned short Kl[128][72];
    __shared__ __align__(16) unsigned short Vt[64][136];
    __shared__ __align__(16) unsigned short Ql[64][72];
    __shared__ __align__(16) unsigned short Ptq[4][16][136];
    __shared__ float mkf[128];

    const int tid = threadIdx.x, wave = tid >> 6, lane = tid & 63;
    const int quad = lane >> 4, l16 = lane & 15;
    const int qi = qbase + wave * 16 + l16;

    {
        int row = tid >> 2, c0 = (tid & 3) * 16;
        const bf16* g = &qkv[(size_t)(tokb + qbase + row) * 2304 + h * 64 + c0];
        *(uint4*)&Ql[row][c0]     = *(const uint4*)(g);
        *(uint4*)&Ql[row][c0 + 8] = *(const uint4*)(g + 8);
    }
    __syncthreads();
    bf16x8 bq[2];
    bq[0] = __builtin_bit_cast(bf16x8, *(const uint4*)&Ql[wave * 16 + l16][quad * 8]);
    bq[1] = __builtin_bit_cast(bf16x8, *(const uint4*)&Ql[wave * 16 + l16][32 + quad * 8]);

    float m_i = -INFINITY, l_i = 0.f;
    f32x4 Oacc[4] = {};

    const int nst = (qbase >> 7) + 1;
    for (int s = 0; s < nst; s++) {
        const int j0 = s * 128;
        __syncthreads();
        {
            int key = tid >> 1, c0 = (tid & 1) * 32;
            const bf16* kg = &qkv[(size_t)(tokb + j0 + key) * 2304 + 768  + h * 64 + c0];
            const bf16* vg = &qkv[(size_t)(tokb + j0 + key) * 2304 + 1536 + h * 64 + c0];
            #pragma unroll
            for (int q = 0; q < 4; q++)
                *(uint4*)&Kl[key][c0 + q * 8] = *(const uint4*)(kg + q * 8);
            union { uint4 u[4]; unsigned short e[32]; } vv;
            #pragma unroll
            for (int q = 0; q < 4; q++) vv.u[q] = *(const uint4*)(vg + q * 8);
            #pragma unroll
            for (int j = 0; j < 32; j++) Vt[c0 + j][key] = vv.e[j];
            if (tid < 128) mkf[tid] = mask[b * 512 + j0 + tid] ? 0.f : -INFINITY;
        }
        __syncthreads();

        f32x4 sc[8] = {};
        #pragma unroll
        for (int kcc = 0; kcc < 8; kcc++) {
            bf16x8 af0 = __builtin_bit_cast(bf16x8, *(const uint4*)&Kl[kcc * 16 + l16][quad * 8]);
            bf16x8 af1 = __builtin_bit_cast(bf16x8, *(const uint4*)&Kl[kcc * 16 + l16][32 + quad * 8]);
            sc[kcc] = __builtin_amdgcn_mfma_f32_16x16x32_bf16(af0, bq[0], sc[kcc], 0, 0, 0);
            sc[kcc] = __builtin_amdgcn_mfma_f32_16x16x32_bf16(af1, bq[1], sc[kcc], 0, 0, 0);
        }

        float pv[8][4];
        float mx = -INFINITY;
        #pragma unroll
        for (int kcc = 0; kcc < 8; kcc++) {
            float4 mk4 = *(const float4*)&mkf[kcc * 16 + quad * 4];
            float mkr[4] = { mk4.x, mk4.y, mk4.z, mk4.w };
            #pragma unroll
            for (int r = 0; r < 4; r++) {
                int krel = kcc * 16 + quad * 4 + r;
                float sval = (j0 + krel <= qi) ? (sc[kcc][r] * 0.125f + mkr[r]) : -INFINITY;
                pv[kcc][r] = sval;
                mx = fmaxf(mx, sval);
            }
        }
        mx = fmaxf(mx, __shfl_xor(mx, 16, 64));
        mx = fmaxf(mx, __shfl_xor(mx, 32, 64));
        float mn = fmaxf(m_i, mx);
        float alpha = (mn == -INFINITY) ? 1.f : __expf(m_i - mn);
        float lsum = 0.f;
        #pragma unroll
        for (int kcc = 0; kcc < 8; kcc++)
            #pragma unroll
            for (int r = 0; r < 4; r++) {
                float pp = (pv[kcc][r] == -INFINITY) ? 0.f : __expf(pv[kcc][r] - mn);
                pv[kcc][r] = pp; lsum += pp;
            }
        lsum += __shfl_xor(lsum, 16, 64);
        lsum += __shfl_xor(lsum, 32, 64);
        m_i = mn; l_i = alpha * l_i + lsum;

        #pragma unroll
        for (int kcc = 0; kcc < 8; kcc++)
            *(uint2*)&Ptq[wave][l16][kcc * 16 + quad * 4] = pack4bf(pv[kcc]);
        #pragma unroll
        for (int mc = 0; mc < 4; mc++)
            #pragma unroll
            for (int r = 0; r < 4; r++) Oacc[mc][r] *= alpha;

        __syncthreads();

        #pragma unroll
        for (int kcc = 0; kcc < 4; kcc++) {
            bf16x8 pb = __builtin_bit_cast(bf16x8, *(const uint4*)&Ptq[wave][l16][kcc * 32 + quad * 8]);
            #pragma unroll
            for (int mc = 0; mc < 4; mc++) {
                bf16x8 vf = __builtin_bit_cast(bf16x8, *(const uint4*)&Vt[mc * 16 + l16][kcc * 32 + quad * 8]);
                Oacc[mc] = __builtin_amdgcn_mfma_f32_16x16x32_bf16(vf, pb, Oacc[mc], 0, 0, 0);
            }
        }
    }

    float inv = (l_i > 0.f) ? 1.f / l_i : 0.f;
    const int tok = tokb + qbase + wave * 16 + l16;
    #pragma unroll
    for (int mc = 0; mc < 4; mc++) {
        float v[4] = { Oacc[mc][0] * inv, Oacc[mc][1] * inv, Oacc[mc][2] * inv, Oacc[mc][3] * inv };
        *(uint2*)&y[(size_t)tok * 768 + h * 64 + mc * 16 + quad * 4] = pack4bf(v);
    }
}

// ---------------- final LN + last-token select + head (fp32) ----------------
__global__ __launch_bounds__(256) void head_k(const float* __restrict__ x, const int* __restrict__ lastidx,
                                              const float* __restrict__ ls, const float* __restrict__ lb,
                                              const float* __restrict__ hw, const float* __restrict__ hb,
                                              float* __restrict__ out)
{
    int b = blockIdx.x, tid = threadIdx.x;
    const float* xr = x + ((size_t)(b * 512 + lastidx[b])) * 768;
    float v0 = xr[tid], v1 = xr[tid + 256], v2 = xr[tid + 512];
    __shared__ float rs[256], rq[256];
    rs[tid] = v0 + v1 + v2; rq[tid] = v0 * v0 + v1 * v1 + v2 * v2;
    __syncthreads();
    for (int st = 128; st > 0; st >>= 1) {
        if (tid < st) { rs[tid] += rs[tid + st]; rq[tid] += rq[tid + st]; }
        __syncthreads();
    }
    float mean = rs[0] * (1.f / 768.f);
    float var  = rq[0] * (1.f / 768.f) - mean * mean;
    float rstd = rsqrtf(var + 1e-5f);
    float part[9];
    #pragma unroll
    for (int a = 0; a < 9; a++) part[a] = 0.f;
    float vv[3] = { v0, v1, v2 };
    #pragma unroll
    for (int e = 0; e < 3; e++) {
        int d = tid + e * 256;
        float xnv = (vv[e] - mean) * rstd * ls[d] + lb[d];
        #pragma unroll
        for (int a = 0; a < 9; a++) part[a] += xnv * hw[d * 9 + a];
    }
    __shared__ float r9[9][256];
    #pragma unroll
    for (int a = 0; a < 9; a++) r9[a][tid] = part[a];
    __syncthreads();
    for (int st = 128; st > 0; st >>= 1) {
        if (tid < st) {
            for (int a = 0; a < 9; a++) r9[a][tid] += r9[a][tid + st];
        }
        __syncthreads();
    }
    if (tid < 9) out[b * 9 + tid] = r9[tid][0] + hb[tid];
}

extern "C" void kernel_launch(void* const* d_in, const int* in_sizes, int n_in,
                              void* d_out, int out_size, void* d_ws, size_t ws_size,
                              hipStream_t stream) {
    const int*   cards   = (const int*)  d_in[0];
    const int*   players = (const int*)  d_in[1];
    const int*   deck    = (const int*)  d_in[2];
    const int*   oppd    = (const int*)  d_in[3];
    const float* tok     = (const float*)d_in[4];
    const float* pemb    = (const float*)d_in[5];
    const float* pos     = (const float*)d_in[6];
    const float* ln1s  = (const float*)d_in[9];
    const float* ln1b  = (const float*)d_in[10];
    const float* qkvw  = (const float*)d_in[11];
    const float* qkvb  = (const float*)d_in[12];
    const float* projw = (const float*)d_in[13];
    const float* projb = (const float*)d_in[14];
    const float* ln2s  = (const float*)d_in[15];
    const float* ln2b  = (const float*)d_in[16];
    const float* fc1w  = (const float*)d_in[17];
    const float* fc1b  = (const float*)d_in[18];
    const float* fc2w  = (const float*)d_in[19];
    const float* fc2b  = (const float*)d_in[20];
    const float* lnfs  = (const float*)d_in[21];
    const float* lnfb  = (const float*)d_in[22];
    const float* hw    = (const float*)d_in[23];
    const float* hb    = (const float*)d_in[24];
    float* out = (float*)d_out;

    char* p = (char*)d_ws;
    auto alloc = [&](size_t bytes) { char* q = p; p += (bytes + 255) & ~((size_t)255); return q; };
    float* x     = (float*)alloc(8192ull * 768 * 4);
    bf16*  xn    = (bf16*) alloc(8192ull * 768 * 2);
    bf16*  big   = (bf16*) alloc(8192ull * 3072 * 2);
    bf16*  wt    = (bf16*) alloc(7077888ull * 2);      // all 4 transposed mats of one layer
    float* deckm = (float*)alloc(2ull * 16 * 768 * 4);
    int*   maskb = (int*)  alloc(8192ull * 4);
    int*   lasti = (int*)  alloc(64);

    bf16* wq = wt;                        // [2304][768]
    bf16* wp = wq + 2304ull * 768;        // [768][768]
    bf16* w1 = wp + 768ull * 768;         // [3072][768]
    bf16* w2 = w1 + 3072ull * 768;        // [768][3072]

    deckmean_k<<<dim3(16, 2), 256, 0, stream>>>(deck, oppd, tok, deckm);
    mask_k<<<16, 512, 0, stream>>>(cards, maskb, lasti);
    embed_k<<<8192, 256, 0, stream>>>(cards, players, tok, pemb, pos, deckm, x);

    for (int i = 0; i < 6; i++) {
        transpose4_k<<<6912, dim3(32, 8), 0, stream>>>(
            qkvw + (size_t)i * 768 * 2304, projw + (size_t)i * 768 * 768,
            fc1w + (size_t)i * 768 * 3072, fc2w + (size_t)i * 3072 * 768,
            wq, wp, w1, w2);

        // attention block
        ln_k<<<8192, 256, 0, stream>>>(x, ln1s + i * 768, ln1b + i * 768, xn);
        gemm128_k<<<64 * 18, 256, 0, stream>>>(xn, wq, qkvb + i * 2304, nullptr, big, 2304, 768, 0, 18);
        attn_k<<<dim3(8, 12, 16), 256, 0, stream>>>(big, maskb, xn);
        gemm64_k<<<128 * 6, 256, 0, stream>>>(xn, wp, projb + i * 768, x, 768, 768, 6);
        // MLP block
        ln_k<<<8192, 256, 0, stream>>>(x, ln2s + i * 768, ln2b + i * 768, xn);
        gemm128_k<<<64 * 24, 256, 0, stream>>>(xn, w1, fc1b + i * 3072, nullptr, big, 3072, 768, 1, 24);
        gemm64_k<<<128 * 6, 256, 0, stream>>>(big, w2, fc2b + i * 768, x, 768, 3072, 6);
    }

    head_k<<<16, 256, 0, stream>>>(x, lasti, lnfs, lnfb, hw, hb, out);
}

// Round 7
// 2047.015 us; speedup vs baseline: 1.2992x; 1.0308x over previous
//
#include <hip/hip_runtime.h>
#include <hip/hip_bf16.h>
#include <math.h>

typedef __hip_bfloat16 bf16;
typedef __bf16 bf16x8 __attribute__((ext_vector_type(8)));
typedef float f32x4 __attribute__((ext_vector_type(4)));

__device__ __forceinline__ float b2f(bf16 v){ return __bfloat162float(v); }
__device__ __forceinline__ bf16  f2b(float v){ return __float2bfloat16(v); }

// tanh-form gelu (~6 VALU ops); max |diff vs erf-gelu| ~1e-3
__device__ __forceinline__ float gelu_f(float v){
    float y = v * (1.f + 0.044715f * v * v);
    return v / (1.f + __expf(-1.5957691216057308f * y));
}

// async global->LDS, 16B per lane; LDS dest = wave-uniform base + lane*16
__device__ __forceinline__ void gl_lds16(const bf16* g, bf16* l) {
    __builtin_amdgcn_global_load_lds((const __attribute__((address_space(1))) unsigned int*)g,
                                     (__attribute__((address_space(3))) unsigned int*)l, 16, 0, 0);
}

__device__ __forceinline__ uint2 pack4bf(const float* v){
    union { unsigned short e[4]; uint2 u; } pk;
    #pragma unroll
    for (int r = 0; r < 4; r++) pk.e[r] = __builtin_bit_cast(unsigned short, f2b(v[r]));
    return pk.u;
}

// ---------------- deck means ----------------
__global__ __launch_bounds__(256) void deckmean_k(const int* __restrict__ deck, const int* __restrict__ opp,
                                                  const float* __restrict__ tok, float* __restrict__ deckm)
{
    int b = blockIdx.x, w = blockIdx.y;
    const int* dk = (w ? opp : deck) + b * 8;
    int idx[8];
    #pragma unroll
    for (int j = 0; j < 8; j++) idx[j] = dk[j];
    float* out = deckm + (size_t)(w * 16 + b) * 768;
    for (int d = threadIdx.x; d < 768; d += 256) {
        float s = 0.f;
        #pragma unroll
        for (int j = 0; j < 8; j++) s += tok[(size_t)idx[j] * 768 + d];
        out[d] = s * 0.125f;
    }
}

// ---------------- mask + last_idx ----------------
__global__ __launch_bounds__(512) void mask_k(const int* __restrict__ cards, int* __restrict__ maskb,
                                              int* __restrict__ lastidx)
{
    int b = blockIdx.x, t = threadIdx.x;
    int m = (cards[b * 512 + t] != 0) ? 1 : 0;
    maskb[b * 512 + t] = m;
    __shared__ int red[512];
    red[t] = m; __syncthreads();
    for (int st = 256; st > 0; st >>= 1) { if (t < st) red[t] += red[t + st]; __syncthreads(); }
    if (t == 0) {
        int cnt = red[0];
        if (cnt == 0) { maskb[b * 512] = 1; cnt = 1; }  // all-pad fix
        lastidx[b] = cnt - 1;
    }
}

// ---------------- embedding sum -> fp32 residual stream ----------------
__global__ __launch_bounds__(256) void embed_k(const int* __restrict__ cards, const int* __restrict__ players,
                                               const float* __restrict__ tok, const float* __restrict__ pemb,
                                               const float* __restrict__ pos, const float* __restrict__ deckm,
                                               float* __restrict__ x)
{
    int t = blockIdx.x;
    int b = t >> 9, ti = t & 511;
    int cd = cards[t];
    int p = players[t]; p = p < 0 ? 0 : (p > 1 ? 1 : p);
    const float* tr  = tok  + (size_t)cd * 768;
    const float* pr  = pemb + (size_t)p  * 768;
    const float* po  = pos  + (size_t)ti * 768;
    const float* dm = deckm + (size_t)b * 768;
    const float* om = deckm + (size_t)(16 + b) * 768;
    float* xr = x + (size_t)t * 768;
    for (int d = threadIdx.x; d < 768; d += 256)
        xr[d] = tr[d] + pr[d] + po[d] + dm[d] + om[d];
}

// ---------------- layernorm (vectorized): fp32 in -> bf16 out, 192 thr/row ----------------
__global__ __launch_bounds__(192) void ln_k(const float* __restrict__ x, const float* __restrict__ s,
                                            const float* __restrict__ b, bf16* __restrict__ out)
{
    int row = blockIdx.x, tid = threadIdx.x;
    float4 v = ((const float4*)(x + (size_t)row * 768))[tid];
    float sum = v.x + v.y + v.z + v.w;
    float sq  = v.x * v.x + v.y * v.y + v.z * v.z + v.w * v.w;
    #pragma unroll
    for (int off = 32; off > 0; off >>= 1) {
        sum += __shfl_xor(sum, off, 64);
        sq  += __shfl_xor(sq,  off, 64);
    }
    __shared__ float red[6];
    int wv = tid >> 6;
    if ((tid & 63) == 0) { red[wv] = sum; red[3 + wv] = sq; }
    __syncthreads();
    float S = red[0] + red[1] + red[2];
    float Q = red[3] + red[4] + red[5];
    float mean = S * (1.f / 768.f);
    float var  = Q * (1.f / 768.f) - mean * mean;
    float rstd = rsqrtf(var + 1e-5f);
    float4 sv = ((const float4*)s)[tid];
    float4 bv = ((const float4*)b)[tid];
    float o[4] = { (v.x - mean) * rstd * sv.x + bv.x, (v.y - mean) * rstd * sv.y + bv.y,
                   (v.z - mean) * rstd * sv.z + bv.z, (v.w - mean) * rstd * sv.w + bv.w };
    ((uint2*)(out + (size_t)row * 768))[tid] = pack4bf(o);
}

// ---------------- weight transpose+downcast: 64x64 tiles, in-register 4x4 transpose ----------------
// tiles: qkv 12x36=432, proj 12x12=144, fc1 12x48=576, fc2 48x12=576 -> 1728 blocks
__global__ __launch_bounds__(256) void transpose4_k(const float* __restrict__ qw, const float* __restrict__ pw,
                                                    const float* __restrict__ f1, const float* __restrict__ f2,
                                                    bf16* __restrict__ oq, bf16* __restrict__ op,
                                                    bf16* __restrict__ o1, bf16* __restrict__ o2)
{
    int t = blockIdx.x;
    const float* in; bf16* out; int K, N, nbx;
    if (t < 432)       { in = qw; out = oq; K = 768;  N = 2304; nbx = 36; }
    else if (t < 576)  { in = pw; out = op; K = 768;  N = 768;  t -= 432;  nbx = 12; }
    else if (t < 1152) { in = f1; out = o1; K = 768;  N = 3072; t -= 576;  nbx = 48; }
    else               { in = f2; out = o2; K = 3072; N = 768;  t -= 1152; nbx = 12; }
    int n0 = (t % nbx) * 64, k0 = (t / nbx) * 64;
    int kq = threadIdx.x & 15, nq = threadIdx.x >> 4;
    float4 rr[4];
    #pragma unroll
    for (int r = 0; r < 4; r++)
        rr[r] = *(const float4*)&in[(size_t)(k0 + kq * 4 + r) * N + n0 + nq * 4];
    const float* fp = (const float*)rr;
    #pragma unroll
    for (int c = 0; c < 4; c++) {
        float v[4] = { fp[c], fp[4 + c], fp[8 + c], fp[12 + c] };
        *(uint2*)&out[(size_t)(n0 + nq * 4 + c) * K + k0 + kq * 4] = pack4bf(v);
    }
}

// ---------------- MFMA GEMM 128x128 (m97 staging + XCD swizzle), swapped operands ----------------
__global__ __launch_bounds__(256) void gemm128_k(const bf16* __restrict__ A, const bf16* __restrict__ BT,
                                                 const float* __restrict__ bias,
                                                 float* __restrict__ outF, bf16* __restrict__ outB,
                                                 int N, int K, int act, int nb)
{
    __shared__ __align__(16) bf16 Al[128 * 64];
    __shared__ __align__(16) bf16 Bl[128 * 64];
    const int tid = threadIdx.x;
    const int lane = tid & 63, wave = tid >> 6;
    const int quad = lane >> 4, l16 = lane & 15;
    const int wm = wave >> 1, wn = wave & 1;

    const int bid = blockIdx.x;
    const int xcd = bid & 7, slot = bid >> 3;
    const int m_loc = slot / nb, nbl = slot - m_loc * nb;
    const int m0 = (xcd * 8 + m_loc) * 128, n0 = nbl * 128;

    f32x4 acc[4][4] = {};
    const int srow = wave * 32;
    const int grow = srow + (lane >> 3);
    const int gcol = (lane & 7) * 8;

    for (int k0 = 0; k0 < K; k0 += 64) {
        #pragma unroll
        for (int i = 0; i < 4; i++) {
            gl_lds16(&A [(size_t)(m0 + grow + i * 8) * K + k0 + gcol], &Al[(srow + i * 8) * 64]);
            gl_lds16(&BT[(size_t)(n0 + grow + i * 8) * K + k0 + gcol], &Bl[(srow + i * 8) * 64]);
        }
        __syncthreads();
        #pragma unroll
        for (int kk = 0; kk < 64; kk += 32) {
            bf16x8 af[4], bfr[4];
            #pragma unroll
            for (int t = 0; t < 4; t++) {
                af[t]  = __builtin_bit_cast(bf16x8, *(const uint4*)(&Al[(wm * 64 + t * 16 + l16) * 64 + kk + quad * 8]));
                bfr[t] = __builtin_bit_cast(bf16x8, *(const uint4*)(&Bl[(wn * 64 + t * 16 + l16) * 64 + kk + quad * 8]));
            }
            #pragma unroll
            for (int tm = 0; tm < 4; tm++)
                #pragma unroll
                for (int tn = 0; tn < 4; tn++)
                    acc[tm][tn] = __builtin_amdgcn_mfma_f32_16x16x32_bf16(bfr[tn], af[tm], acc[tm][tn], 0, 0, 0);
        }
        __syncthreads();
    }

    float4 bv[4];
    #pragma unroll
    for (int tn = 0; tn < 4; tn++)
        bv[tn] = *(const float4*)&bias[n0 + wn * 64 + tn * 16 + quad * 4];

    #pragma unroll
    for (int tm = 0; tm < 4; tm++) {
        int m = m0 + wm * 64 + tm * 16 + l16;
        #pragma unroll
        for (int tn = 0; tn < 4; tn++) {
            int nbase = n0 + wn * 64 + tn * 16 + quad * 4;
            float v[4] = { acc[tm][tn][0] + bv[tn].x, acc[tm][tn][1] + bv[tn].y,
                           acc[tm][tn][2] + bv[tn].z, acc[tm][tn][3] + bv[tn].w };
            if (act) {
                #pragma unroll
                for (int r = 0; r < 4; r++) v[r] = gelu_f(v[r]);
            }
            size_t off = (size_t)m * N + nbase;
            if (outB) *(uint2*)&outB[off] = pack4bf(v);
            else      *(float4*)&outF[off] = make_float4(v[0], v[1], v[2], v[3]);
        }
    }
}

// ---------------- MFMA GEMM 64x128 (narrow-N: proj, fc2), float4 residual RMW ----------------
__global__ __launch_bounds__(256) void gemm64_k(const bf16* __restrict__ A, const bf16* __restrict__ BT,
                                                const float* __restrict__ bias,
                                                float* __restrict__ x, int N, int K, int nb)
{
    __shared__ __align__(16) bf16 Al[64 * 64];
    __shared__ __align__(16) bf16 Bl[128 * 64];
    const int tid = threadIdx.x;
    const int lane = tid & 63, wave = tid >> 6;
    const int quad = lane >> 4, l16 = lane & 15;
    const int wm = wave >> 1, wn = wave & 1;

    const int bid = blockIdx.x;
    const int xcd = bid & 7, slot = bid >> 3;
    const int m_loc = slot / nb, nbl = slot - m_loc * nb;
    const int m0 = (xcd * 16 + m_loc) * 64, n0 = nbl * 128;

    f32x4 acc[2][4] = {};
    const int srow = wave * 8 + (lane >> 3);
    const int gcol = (lane & 7) * 8;

    for (int k0 = 0; k0 < K; k0 += 64) {
        #pragma unroll
        for (int i = 0; i < 2; i++)
            gl_lds16(&A [(size_t)(m0 + srow + i * 32) * K + k0 + gcol], &Al[(wave * 8 + i * 32) * 64]);
        #pragma unroll
        for (int i = 0; i < 4; i++)
            gl_lds16(&BT[(size_t)(n0 + srow + i * 32) * K + k0 + gcol], &Bl[(wave * 8 + i * 32) * 64]);
        __syncthreads();
        #pragma unroll
        for (int kk = 0; kk < 64; kk += 32) {
            bf16x8 af[2], bfr[4];
            #pragma unroll
            for (int t = 0; t < 2; t++)
                af[t]  = __builtin_bit_cast(bf16x8, *(const uint4*)(&Al[(wm * 32 + t * 16 + l16) * 64 + kk + quad * 8]));
            #pragma unroll
            for (int t = 0; t < 4; t++)
                bfr[t] = __builtin_bit_cast(bf16x8, *(const uint4*)(&Bl[(wn * 64 + t * 16 + l16) * 64 + kk + quad * 8]));
            #pragma unroll
            for (int tm = 0; tm < 2; tm++)
                #pragma unroll
                for (int tn = 0; tn < 4; tn++)
                    acc[tm][tn] = __builtin_amdgcn_mfma_f32_16x16x32_bf16(bfr[tn], af[tm], acc[tm][tn], 0, 0, 0);
        }
        __syncthreads();
    }

    float4 bv[4];
    #pragma unroll
    for (int tn = 0; tn < 4; tn++)
        bv[tn] = *(const float4*)&bias[n0 + wn * 64 + tn * 16 + quad * 4];

    #pragma unroll
    for (int tm = 0; tm < 2; tm++) {
        int m = m0 + wm * 32 + tm * 16 + l16;
        #pragma unroll
        for (int tn = 0; tn < 4; tn++) {
            int nbase = n0 + wn * 64 + tn * 16 + quad * 4;
            float* xp = &x[(size_t)m * N + nbase];
            float4 xo = *(float4*)xp;
            xo.x += acc[tm][tn][0] + bv[tn].x;
            xo.y += acc[tm][tn][1] + bv[tn].y;
            xo.z += acc[tm][tn][2] + bv[tn].z;
            xo.w += acc[tm][tn][3] + bv[tn].w;
            *(float4*)xp = xo;      // splitK=1: no race
        }
    }
}

// ---------------- MFMA flash attention: 128 queries/block ----------------
// grid (qt=4, h=12, b=16); block 256 = 4 waves; wave w owns queries w*32..w*32+31 (2 chunks of 16).
// Q-fragments loaded direct from global (no Ql LDS); K/V staged once per 128-key stage, feeds 2 chunks.
__global__ __launch_bounds__(256) void attn_k(const bf16* __restrict__ qkv, const int* __restrict__ mask,
                                              bf16* __restrict__ y)
{
    const int qt = blockIdx.x, h = blockIdx.y, b = blockIdx.z;
    const int qbase = qt * 128, tokb = b * 512;
    __shared__ __align__(16) unsigned short Kl[128][72];
    __shared__ __align__(16) unsigned short Vt[64][136];
    __shared__ __align__(16) unsigned short Ptq[4][16][136];
    __shared__ float mkf[128];

    const int tid = threadIdx.x, wave = tid >> 6, lane = tid & 63;
    const int quad = lane >> 4, l16 = lane & 15;

    // Q fragments for both chunks, direct from global (L2-resident)
    bf16x8 bq[2][2];
    #pragma unroll
    for (int qc = 0; qc < 2; qc++) {
        const bf16* qp = &qkv[(size_t)(tokb + qbase + wave * 32 + qc * 16 + l16) * 2304 + h * 64];
        bq[qc][0] = __builtin_bit_cast(bf16x8, *(const uint4*)(qp + quad * 8));
        bq[qc][1] = __builtin_bit_cast(bf16x8, *(const uint4*)(qp + 32 + quad * 8));
    }

    float m_i[2] = { -INFINITY, -INFINITY }, l_i[2] = { 0.f, 0.f };
    f32x4 Oacc[2][4] = {};

    const int nst = qt + 1;
    for (int s = 0; s < nst; s++) {
        const int j0 = s * 128;
        __syncthreads();    // WAR: Kl/Vt/Ptq from previous stage
        {   // stage K row-major, V transposed, pad-mask as additive -inf
            int key = tid >> 1, c0 = (tid & 1) * 32;
            const bf16* kg = &qkv[(size_t)(tokb + j0 + key) * 2304 + 768  + h * 64 + c0];
            const bf16* vg = &qkv[(size_t)(tokb + j0 + key) * 2304 + 1536 + h * 64 + c0];
            #pragma unroll
            for (int q = 0; q < 4; q++)
                *(uint4*)&Kl[key][c0 + q * 8] = *(const uint4*)(kg + q * 8);
            union { uint4 u[4]; unsigned short e[32]; } vv;
            #pragma unroll
            for (int q = 0; q < 4; q++) vv.u[q] = *(const uint4*)(vg + q * 8);
            #pragma unroll
            for (int j = 0; j < 32; j++) Vt[c0 + j][key] = vv.e[j];
            if (tid < 128) mkf[tid] = mask[b * 512 + j0 + tid] ? 0.f : -INFINITY;
        }
        __syncthreads();

        #pragma unroll
        for (int qc = 0; qc < 2; qc++) {
            const int qi = qbase + wave * 32 + qc * 16 + l16;

            // S^T = K · Q^T
            f32x4 sc[8] = {};
            #pragma unroll
            for (int kcc = 0; kcc < 8; kcc++) {
                bf16x8 af0 = __builtin_bit_cast(bf16x8, *(const uint4*)&Kl[kcc * 16 + l16][quad * 8]);
                bf16x8 af1 = __builtin_bit_cast(bf16x8, *(const uint4*)&Kl[kcc * 16 + l16][32 + quad * 8]);
                sc[kcc] = __builtin_amdgcn_mfma_f32_16x16x32_bf16(af0, bq[qc][0], sc[kcc], 0, 0, 0);
                sc[kcc] = __builtin_amdgcn_mfma_f32_16x16x32_bf16(af1, bq[qc][1], sc[kcc], 0, 0, 0);
            }

            float pv[8][4];
            float mx = -INFINITY;
            #pragma unroll
            for (int kcc = 0; kcc < 8; kcc++) {
                float4 mk4 = *(const float4*)&mkf[kcc * 16 + quad * 4];
                float mkr[4] = { mk4.x, mk4.y, mk4.z, mk4.w };
                #pragma unroll
                for (int r = 0; r < 4; r++) {
                    int krel = kcc * 16 + quad * 4 + r;
                    float sval = (j0 + krel <= qi) ? (sc[kcc][r] * 0.125f + mkr[r]) : -INFINITY;
                    pv[kcc][r] = sval;
                    mx = fmaxf(mx, sval);
                }
            }
            mx = fmaxf(mx, __shfl_xor(mx, 16, 64));
            mx = fmaxf(mx, __shfl_xor(mx, 32, 64));
            float mn = fmaxf(m_i[qc], mx);
            float alpha = (mn == -INFINITY) ? 1.f : __expf(m_i[qc] - mn);
            float lsum = 0.f;
            #pragma unroll
            for (int kcc = 0; kcc < 8; kcc++)
                #pragma unroll
                for (int r = 0; r < 4; r++) {
                    float pp = (pv[kcc][r] == -INFINITY) ? 0.f : __expf(pv[kcc][r] - mn);
                    pv[kcc][r] = pp; lsum += pp;
                }
            lsum += __shfl_xor(lsum, 16, 64);
            lsum += __shfl_xor(lsum, 32, 64);
            m_i[qc] = mn; l_i[qc] = alpha * l_i[qc] + lsum;

            #pragma unroll
            for (int kcc = 0; kcc < 8; kcc++)
                *(uint2*)&Ptq[wave][l16][kcc * 16 + quad * 4] = pack4bf(pv[kcc]);
            #pragma unroll
            for (int mc = 0; mc < 4; mc++)
                #pragma unroll
                for (int r = 0; r < 4; r++) Oacc[qc][mc][r] *= alpha;

            __syncthreads();   // uniform across waves (same qc sequence)

            #pragma unroll
            for (int kcc = 0; kcc < 4; kcc++) {
                bf16x8 pb = __builtin_bit_cast(bf16x8, *(const uint4*)&Ptq[wave][l16][kcc * 32 + quad * 8]);
                #pragma unroll
                for (int mc = 0; mc < 4; mc++) {
                    bf16x8 vf = __builtin_bit_cast(bf16x8, *(const uint4*)&Vt[mc * 16 + l16][kcc * 32 + quad * 8]);
                    Oacc[qc][mc] = __builtin_amdgcn_mfma_f32_16x16x32_bf16(vf, pb, Oacc[qc][mc], 0, 0, 0);
                }
            }
        }
    }

    #pragma unroll
    for (int qc = 0; qc < 2; qc++) {
        float inv = (l_i[qc] > 0.f) ? 1.f / l_i[qc] : 0.f;   // fully-masked row -> 0
        const int tok = tokb + qbase + wave * 32 + qc * 16 + l16;
        #pragma unroll
        for (int mc = 0; mc < 4; mc++) {
            float v[4] = { Oacc[qc][mc][0] * inv, Oacc[qc][mc][1] * inv,
                           Oacc[qc][mc][2] * inv, Oacc[qc][mc][3] * inv };
            *(uint2*)&y[(size_t)tok * 768 + h * 64 + mc * 16 + quad * 4] = pack4bf(v);
        }
    }
}

// ---------------- final LN + last-token select + head (fp32) ----------------
__global__ __launch_bounds__(256) void head_k(const float* __restrict__ x, const int* __restrict__ lastidx,
                                              const float* __restrict__ ls, const float* __restrict__ lb,
                                              const float* __restrict__ hw, const float* __restrict__ hb,
                                              float* __restrict__ out)
{
    int b = blockIdx.x, tid = threadIdx.x;
    const float* xr = x + ((size_t)(b * 512 + lastidx[b])) * 768;
    float v0 = xr[tid], v1 = xr[tid + 256], v2 = xr[tid + 512];
    __shared__ float rs[256], rq[256];
    rs[tid] = v0 + v1 + v2; rq[tid] = v0 * v0 + v1 * v1 + v2 * v2;
    __syncthreads();
    for (int st = 128; st > 0; st >>= 1) {
        if (tid < st) { rs[tid] += rs[tid + st]; rq[tid] += rq[tid + st]; }
        __syncthreads();
    }
    float mean = rs[0] * (1.f / 768.f);
    float var  = rq[0] * (1.f / 768.f) - mean * mean;
    float rstd = rsqrtf(var + 1e-5f);
    float part[9];
    #pragma unroll
    for (int a = 0; a < 9; a++) part[a] = 0.f;
    float vv[3] = { v0, v1, v2 };
    #pragma unroll
    for (int e = 0; e < 3; e++) {
        int d = tid + e * 256;
        float xnv = (vv[e] - mean) * rstd * ls[d] + lb[d];
        #pragma unroll
        for (int a = 0; a < 9; a++) part[a] += xnv * hw[d * 9 + a];
    }
    __shared__ float r9[9][256];
    #pragma unroll
    for (int a = 0; a < 9; a++) r9[a][tid] = part[a];
    __syncthreads();
    for (int st = 128; st > 0; st >>= 1) {
        if (tid < st) {
            for (int a = 0; a < 9; a++) r9[a][tid] += r9[a][tid + st];
        }
        __syncthreads();
    }
    if (tid < 9) out[b * 9 + tid] = r9[tid][0] + hb[tid];
}

extern "C" void kernel_launch(void* const* d_in, const int* in_sizes, int n_in,
                              void* d_out, int out_size, void* d_ws, size_t ws_size,
                              hipStream_t stream) {
    const int*   cards   = (const int*)  d_in[0];
    const int*   players = (const int*)  d_in[1];
    const int*   deck    = (const int*)  d_in[2];
    const int*   oppd    = (const int*)  d_in[3];
    const float* tok     = (const float*)d_in[4];
    const float* pemb    = (const float*)d_in[5];
    const float* pos     = (const float*)d_in[6];
    const float* ln1s  = (const float*)d_in[9];
    const float* ln1b  = (const float*)d_in[10];
    const float* qkvw  = (const float*)d_in[11];
    const float* qkvb  = (const float*)d_in[12];
    const float* projw = (const float*)d_in[13];
    const float* projb = (const float*)d_in[14];
    const float* ln2s  = (const float*)d_in[15];
    const float* ln2b  = (const float*)d_in[16];
    const float* fc1w  = (const float*)d_in[17];
    const float* fc1b  = (const float*)d_in[18];
    const float* fc2w  = (const float*)d_in[19];
    const float* fc2b  = (const float*)d_in[20];
    const float* lnfs  = (const float*)d_in[21];
    const float* lnfb  = (const float*)d_in[22];
    const float* hw    = (const float*)d_in[23];
    const float* hb    = (const float*)d_in[24];
    float* out = (float*)d_out;

    char* p = (char*)d_ws;
    auto alloc = [&](size_t bytes) { char* q = p; p += (bytes + 255) & ~((size_t)255); return q; };
    float* x     = (float*)alloc(8192ull * 768 * 4);
    bf16*  xn    = (bf16*) alloc(8192ull * 768 * 2);
    bf16*  big   = (bf16*) alloc(8192ull * 3072 * 2);
    bf16*  wt    = (bf16*) alloc(7077888ull * 2);      // all 4 transposed mats of one layer
    float* deckm = (float*)alloc(2ull * 16 * 768 * 4);
    int*   maskb = (int*)  alloc(8192ull * 4);
    int*   lasti = (int*)  alloc(64);

    bf16* wq = wt;                        // [2304][768]
    bf16* wp = wq + 2304ull * 768;        // [768][768]
    bf16* w1 = wp + 768ull * 768;         // [3072][768]
    bf16* w2 = w1 + 3072ull * 768;        // [768][3072]

    deckmean_k<<<dim3(16, 2), 256, 0, stream>>>(deck, oppd, tok, deckm);
    mask_k<<<16, 512, 0, stream>>>(cards, maskb, lasti);
    embed_k<<<8192, 256, 0, stream>>>(cards, players, tok, pemb, pos, deckm, x);

    for (int i = 0; i < 6; i++) {
        transpose4_k<<<1728, 256, 0, stream>>>(
            qkvw + (size_t)i * 768 * 2304, projw + (size_t)i * 768 * 768,
            fc1w + (size_t)i * 768 * 3072, fc2w + (size_t)i * 3072 * 768,
            wq, wp, w1, w2);

        // attention block
        ln_k<<<8192, 192, 0, stream>>>(x, ln1s + i * 768, ln1b + i * 768, xn);
        gemm128_k<<<64 * 18, 256, 0, stream>>>(xn, wq, qkvb + i * 2304, nullptr, big, 2304, 768, 0, 18);
        attn_k<<<dim3(4, 12, 16), 256, 0, stream>>>(big, maskb, xn);
        gemm64_k<<<128 * 6, 256, 0, stream>>>(xn, wp, projb + i * 768, x, 768, 768, 6);
        // MLP block
        ln_k<<<8192, 192, 0, stream>>>(x, ln2s + i * 768, ln2b + i * 768, xn);
        gemm128_k<<<64 * 24, 256, 0, stream>>>(xn, w1, fc1b + i * 3072, nullptr, big, 3072, 768, 1, 24);
        gemm64_k<<<128 * 6, 256, 0, stream>>>(big, w2, fc2b + i * 768, x, 768, 3072, 6);
    }

    head_k<<<16, 256, 0, stream>>>(x, lasti, lnfs, lnfb, hw, hb, out);
}